// Round 6
// baseline (310.314 us; speedup 1.0000x reference)
//
// MemFullAttention_19585050870313 — MI355X round 5
// Change vs round 4: GEMM phase schedule rebuilt as read-prefetch-balanced:
//   - exactly 6 ds_read_b128 per phase (was 12/4/8/0) -> LDS pipe 576 cyc/phase < MFMA 620
//   - reads issued one phase EARLY (post-MM), double-buffered regs aX/aY/bP/bQ
//   - vmcnt(6) at every phase end (global stage-landing guard, distance-4 proof)
// prep / attn_fwd unchanged from round 4.
#include <hip/hip_runtime.h>
#include <hip/hip_bf16.h>

typedef __bf16 bf16;
typedef __bf16 bf16x8 __attribute__((ext_vector_type(8)));
typedef float  f32x4  __attribute__((ext_vector_type(4)));
typedef float  f32x4v __attribute__((ext_vector_type(4)));
typedef unsigned int u32x4 __attribute__((ext_vector_type(4)));
typedef unsigned short u16x4 __attribute__((ext_vector_type(4)));

#define DEV __device__ __forceinline__

DEV void gload_lds16(const bf16* g, bf16* l) {
    __builtin_amdgcn_global_load_lds(
        (__attribute__((address_space(1))) void*)g,
        (__attribute__((address_space(3))) void*)l, 16, 0, 0);
}

DEV bf16x8 as_bf(u32x4 v) { return __builtin_bit_cast(bf16x8, v); }

DEV f32x4 mfma16(bf16x8 a, bf16x8 b, f32x4 c) {
    return __builtin_amdgcn_mfma_f32_16x16x32_bf16(a, b, c, 0, 0, 0);
}

DEV int cvtpk(float lo, float hi) {
    int r;
    asm("v_cvt_pk_bf16_f32 %0, %1, %2" : "=v"(r) : "v"(lo), "v"(hi));
    return r;
}

// ---- problem constants (reference_length fixed at 3) ----
constexpr int D_   = 1024;
constexpr int S_   = 256;
constexpr int TOUT = 11;
constexpr int MQ   = 4 * TOUT * S_;   // 11264
constexpr int MKV  = 4 * 8 * 3 * S_;  // 24576
constexpr int KVL  = 768;

constexpr int PB_WQKV = 768;
constexpr int PB_WOUT = 256;
constexpr int PB_GQ   = MQ  * 128 / 256;     // 5632
constexpr int PB_GKV  = MKV * 128 / 256;     // 12288
constexpr int PB_TOT  = PB_WQKV + PB_WOUT + PB_GQ + PB_GKV;

// ======================= fused prep (unchanged) =====================
__global__ void prep(const float* __restrict__ x,
                     const float* __restrict__ Wqkv,
                     const float* __restrict__ Wout,
                     bf16* __restrict__ Aq, bf16* __restrict__ Akv,
                     bf16* __restrict__ Wqkv_t, bf16* __restrict__ Wout_t)
{
    __shared__ float T[64][65];
    const int tid = threadIdx.x;
    int wg = blockIdx.x;

    if (wg < PB_WQKV + PB_WOUT) {
        const float* W; bf16* Wt; int N, bid2;
        if (wg < PB_WQKV) { W = Wqkv; Wt = Wqkv_t; N = 3072; bid2 = wg; }
        else              { W = Wout; Wt = Wout_t; N = 1024; bid2 = wg - PB_WQKV; }
        const int kt = bid2 & 15, nt = bid2 >> 4;
        const int k0 = kt * 64, n0 = nt * 64;
        for (int i = 0; i < 16; ++i) {
            const int e = i * 256 + tid;
            const int kk = e >> 6, nn = e & 63;
            T[nn][kk] = W[(size_t)(k0 + kk) * N + n0 + nn];
        }
        __syncthreads();
        for (int i = 0; i < 16; ++i) {
            const int e = i * 256 + tid;
            const int n = e >> 6, kk = e & 63;
            Wt[(size_t)(n0 + n) * 1024 + k0 + kk] = (bf16)T[n][kk];
        }
        return;
    }
    wg -= PB_WQKV + PB_WOUT;

    int row, part;
    const float* src;
    bf16* dst;
    if (wg < PB_GQ) {
        const int idx = wg * 256 + tid;
        row = idx >> 7; part = idx & 127;
        const int b    = row / (TOUT * S_);
        const int r2   = row - b * (TOUT * S_);
        const int tout = r2 >> 8;
        const int s    = r2 & 255;
        const int tx   = tout < 7 ? tout * 4 : 28 + (tout - 7);
        src = x + ((size_t)((b * 32 + tx) * S_ + s)) * D_ + part * 8;
        dst = Aq + (size_t)row * D_ + part * 8;
    } else {
        const int idx = (wg - PB_GQ) * 256 + tid;
        row = idx >> 7; part = idx & 127;
        const int b  = row / 6144;
        const int r2 = row - b * 6144;
        const int c  = r2 / KVL;
        const int j  = r2 - c * KVL;
        const int f  = 1 + (j >> 8);
        const int s  = j & 255;
        const int tx = c * 4 + f;
        src = x + ((size_t)((b * 32 + tx) * S_ + s)) * D_ + part * 8;
        dst = Akv + (size_t)row * D_ + part * 8;
    }
    f32x4v v0 = *(const f32x4v*)src;
    f32x4v v1 = *(const f32x4v*)(src + 4);
    bf16x8 o;
    o[0]=(bf16)v0[0]; o[1]=(bf16)v0[1]; o[2]=(bf16)v0[2]; o[3]=(bf16)v0[3];
    o[4]=(bf16)v1[0]; o[5]=(bf16)v1[1]; o[6]=(bf16)v1[2]; o[7]=(bf16)v1[3];
    *(bf16x8*)dst = o;
}

// ======================= 8-phase GEMM, balanced read-prefetch =======
#define PH_BEGIN() do { \
    __builtin_amdgcn_s_barrier(); \
    asm volatile("s_waitcnt lgkmcnt(0)" ::: "memory"); \
    __builtin_amdgcn_sched_barrier(0); \
    __builtin_amdgcn_s_setprio(1); \
} while(0)

#define PH_MMEND() do { \
    __builtin_amdgcn_s_setprio(0); \
    __builtin_amdgcn_sched_barrier(0); \
} while(0)

#define PH_CLOSE() do { \
    asm volatile("s_waitcnt vmcnt(6)" ::: "memory"); \
    __builtin_amdgcn_s_barrier(); \
} while(0)

#define STAGE_A(bufc, half, tile) do { \
    const bf16* s0_ = pA + (size_t)(half) * 64 * 1024 + (tile) * 64; \
    bf16* d0_ = ldsA + (bufc) * 16384 + (half) * 8192; \
    gload_lds16(s0_, d0_); \
    gload_lds16(s0_ + (size_t)128 * 1024, d0_ + 4096); \
} while(0)

#define STAGE_B(bufc, half, tile) do { \
    const bf16* s0_ = pB + (size_t)(half) * 32 * 1024 + (tile) * 64; \
    bf16* d0_ = ldsB + (bufc) * 16384 + (half) * 8192; \
    gload_lds16(s0_, d0_); \
    gload_lds16(s0_ + (size_t)128 * 1024, d0_ + 4096); \
} while(0)

// 2 ds_read_b128: one A j-frag (both k-slices)
#define LDAJ(dst, bufc, mh, J) do { \
    const bf16* p_ = sm + (bufc) * 16384 + (mh) * 8192 + (J) * 1024; \
    dst[J][0] = *(const u32x4*)(p_ + eA0); \
    dst[J][1] = *(const u32x4*)(p_ + eA1); \
} while(0)

// 4 ds_read_b128: both B i-frags of one half
#define LDBH(dst, bufc, nh) do { \
    const bf16* p_ = sm + 32768 + (bufc) * 16384 + (nh) * 8192; \
    dst[0][0] = *(const u32x4*)(p_ + eB0); \
    dst[0][1] = *(const u32x4*)(p_ + eB1); \
    dst[1][0] = *(const u32x4*)(p_ + 1024 + eB0); \
    dst[1][1] = *(const u32x4*)(p_ + 1024 + eB1); \
} while(0)

#define MMX(av, bv, mh, nh) do { \
    _Pragma("unroll") \
    for (int j_ = 0; j_ < 4; ++j_) { \
        _Pragma("unroll") \
        for (int i_ = 0; i_ < 2; ++i_) { \
            f32x4 c_ = acc[(mh)*4 + j_][(nh)*2 + i_]; \
            c_ = mfma16(as_bf(av[j_][0]), as_bf(bv[i_][0]), c_); \
            c_ = mfma16(as_bf(av[j_][1]), as_bf(bv[i_][1]), c_); \
            acc[(mh)*4 + j_][(nh)*2 + i_] = c_; \
        } \
    } \
} while(0)

// Schedule (per iter t: buf0=tile 2t, buf1=2t+1; stages n0=2t+2, n1=2t+3):
//  ph1 stage A1h1(2t+1) | MM(aX,bP,0,0) | read bQ(0,1)+aY(0,1,j0)
//  ph2 stage A0h0(n0)   | MM(aX,bQ,0,1) | read aY(0,1,j1..3)
//  ph3 stage B0h0(n0)   | MM(aY,bP,1,0) | read aX(1,0,j0..2)
//  ph4 stage B0h1(n0)   | MM(aY,bQ,1,1) | read aX(1,0,j3)+bP(1,0)
//  ph5 stage A0h1(n0)   | MM(aX,bP,0,0) | read bQ(1,1)+aY(1,1,j0)
//  ph6 stage A1h0(n1)   | MM(aX,bQ,0,1) | read aY(1,1,j1..3)
//  ph7 stage B1h0(n1)   | MM(aY,bP,1,0) | read aX(0,0,j0..2)'
//  ph8 stage B1h1(n1)   | MM(aY,bQ,1,1) | read aX(0,0,j3)'+bP(0,0)'
// Every read's stage-distance >= 4 (guarded by per-phase vmcnt(6)+barrier);
// every stage's slot had its last reg-read >= 2 phases earlier.
#define GEMM_MAINLOOP() do { \
    STAGE_A(0, 0, 0); STAGE_A(0, 1, 0); STAGE_B(0, 0, 0); STAGE_B(0, 1, 0); \
    STAGE_A(1, 0, 1); STAGE_B(1, 0, 1); STAGE_B(1, 1, 1); \
    asm volatile("s_waitcnt vmcnt(6)" ::: "memory"); \
    __builtin_amdgcn_s_barrier(); \
    LDAJ(aX,0,0,0); LDAJ(aX,0,0,1); LDAJ(aX,0,0,2); LDAJ(aX,0,0,3); \
    LDBH(bP,0,0); \
    _Pragma("unroll 1") \
    for (int t = 0; t < 8; ++t) { \
        const int T1 = 2 * t + 1; \
        const int n0 = (2 * t + 2 < 15) ? 2 * t + 2 : 15; \
        const int n1 = (2 * t + 3 < 15) ? 2 * t + 3 : 15; \
        STAGE_A(1, 1, T1); \
        PH_BEGIN(); MMX(aX, bP, 0, 0); PH_MMEND(); \
        LDBH(bQ, 0, 1); LDAJ(aY, 0, 1, 0); \
        PH_CLOSE(); \
        STAGE_A(0, 0, n0); \
        PH_BEGIN(); MMX(aX, bQ, 0, 1); PH_MMEND(); \
        LDAJ(aY, 0, 1, 1); LDAJ(aY, 0, 1, 2); LDAJ(aY, 0, 1, 3); \
        PH_CLOSE(); \
        STAGE_B(0, 0, n0); \
        PH_BEGIN(); MMX(aY, bP, 1, 0); PH_MMEND(); \
        LDAJ(aX, 1, 0, 0); LDAJ(aX, 1, 0, 1); LDAJ(aX, 1, 0, 2); \
        PH_CLOSE(); \
        STAGE_B(0, 1, n0); \
        PH_BEGIN(); MMX(aY, bQ, 1, 1); PH_MMEND(); \
        LDAJ(aX, 1, 0, 3); LDBH(bP, 1, 0); \
        PH_CLOSE(); \
        STAGE_A(0, 1, n0); \
        PH_BEGIN(); MMX(aX, bP, 0, 0); PH_MMEND(); \
        LDBH(bQ, 1, 1); LDAJ(aY, 1, 1, 0); \
        PH_CLOSE(); \
        STAGE_A(1, 0, n1); \
        PH_BEGIN(); MMX(aX, bQ, 0, 1); PH_MMEND(); \
        LDAJ(aY, 1, 1, 1); LDAJ(aY, 1, 1, 2); LDAJ(aY, 1, 1, 3); \
        PH_CLOSE(); \
        STAGE_B(1, 0, n1); \
        PH_BEGIN(); MMX(aY, bP, 1, 0); PH_MMEND(); \
        LDAJ(aX, 0, 0, 0); LDAJ(aX, 0, 0, 1); LDAJ(aX, 0, 0, 2); \
        PH_CLOSE(); \
        STAGE_B(1, 1, n1); \
        PH_BEGIN(); MMX(aY, bQ, 1, 1); PH_MMEND(); \
        LDAJ(aX, 0, 0, 3); LDBH(bP, 0, 0); \
        PH_CLOSE(); \
    } \
    asm volatile("s_waitcnt vmcnt(0) lgkmcnt(0)" ::: "memory"); \
} while(0)

#define GEMM_PREAMBLE() \
    const int wr = wid >> 2, wc = wid & 3; \
    const int l15 = lane & 15, l4 = lane >> 4; \
    const int Rrow = (wid << 3) + (lane >> 3); \
    const int G    = (lane & 7) ^ (lane >> 3); \
    const bf16* pA = A  + (size_t)(bm * 256 + Rrow) * 1024 + G * 8; \
    const int wc1 = Rrow >> 5, cc1 = Rrow & 31; \
    const bf16* pB = Bt + (size_t)(bn * 256 + wc1 * 64 + cc1) * 1024 + G * 8; \
    bf16* ldsA = sm + (wid << 9); \
    bf16* ldsB = sm + 32768 + (wid << 9); \
    const int g0  = l4 ^ (l15 & 7); \
    const int eA0 = wr * 4096 + l15 * 64 + g0 * 8; \
    const int eA1 = eA0 ^ 32; \
    const int eB0 = wc * 2048 + l15 * 64 + g0 * 8; \
    const int eB1 = eB0 ^ 32; \
    f32x4 acc[8][4]; \
    u32x4 aX[4][2], aY[4][2], bP[2][2], bQ[2][2]; \
    { const f32x4 zf_ = {0.f, 0.f, 0.f, 0.f}; \
      _Pragma("unroll") \
      for (int m_ = 0; m_ < 8; ++m_) \
          _Pragma("unroll") \
          for (int n_ = 0; n_ < 4; ++n_) acc[m_][n_] = zf_; }

// ======================= fused Q+KV projection GEMM =================
__global__ __launch_bounds__(512, 2) void gemm_qkv(
    const bf16* __restrict__ Aq, const bf16* __restrict__ Akv,
    const bf16* __restrict__ Wt,
    bf16* __restrict__ Qb, bf16* __restrict__ Kb, bf16* __restrict__ Vt)
{
    __shared__ bf16 sm[65536];
    const int tid = threadIdx.x, lane = tid & 63, wid = tid >> 6;

    int wg = blockIdx.x;
    {   // bijective XCD swizzle, nwg=944
        const int xcd = wg & 7, off = wg >> 3;
        wg = xcd * 118 + off;
    }
    const bool isQ = wg < 176;
    const bf16* A;  const bf16* Bt;  int bm, bn;
    if (isQ) { A = Aq;  Bt = Wt;                       bm = wg % 44;  bn = wg / 44; }
    else     { wg -= 176;
               A = Akv; Bt = Wt + (size_t)1024 * 1024; bm = wg % 96;  bn = wg / 96; }

    GEMM_PREAMBLE();
    GEMM_MAINLOOP();

    if (isQ || bn < 4) {
        bf16* C = isQ ? Qb : Kb;
        #pragma unroll
        for (int m = 0; m < 8; ++m) {
            const int row = bm * 256 + wr * 128 + m * 16 + l4 * 4;
            #pragma unroll
            for (int n = 0; n < 4; ++n) {
                const int col = bn * 256 + wc * 64 + n * 16 + l15;
                f32x4 v = acc[m][n];
                #pragma unroll
                for (int r = 0; r < 4; ++r)
                    C[(size_t)(row + r) * 1024 + col] = (bf16)v[r];
            }
        }
    } else {
        const int vb = bm / 3;
        const int j0base = (bm % 3) * 256;
        #pragma unroll
        for (int m = 0; m < 8; ++m) {
            const int j0 = j0base + wr * 128 + m * 16 + l4 * 4;
            #pragma unroll
            for (int n = 0; n < 4; ++n) {
                const int colv = (bn - 4) * 256 + wc * 64 + n * 16 + l15;
                f32x4 v = acc[m][n];
                u16x4 pk;
                #pragma unroll
                for (int r = 0; r < 4; ++r) {
                    bf16 t = (bf16)v[r];
                    pk[r] = __builtin_bit_cast(unsigned short, t);
                }
                *(u16x4*)(Vt + ((size_t)vb * 1024 + colv) * KVL + j0) = pk;
            }
        }
    }
}

// ======================= out GEMM ===================================
__global__ __launch_bounds__(512, 2) void gemm_out(
    const bf16* __restrict__ A, const bf16* __restrict__ Bt,
    float* __restrict__ Cf, const float* __restrict__ bias)
{
    __shared__ bf16 sm[65536];
    const int tid = threadIdx.x, lane = tid & 63, wid = tid >> 6;

    int wg = blockIdx.x;
    {   // nwg=176: q=22
        const int xcd = wg & 7, off = wg >> 3;
        wg = xcd * 22 + off;
    }
    const int bm = wg % 44, bn = wg / 44;

    GEMM_PREAMBLE();
    GEMM_MAINLOOP();

    #pragma unroll
    for (int m = 0; m < 8; ++m) {
        const int row = bm * 256 + wr * 128 + m * 16 + l4 * 4;
        #pragma unroll
        for (int n = 0; n < 4; ++n) {
            const int col = bn * 256 + wc * 64 + n * 16 + l15;
            f32x4 v = acc[m][n];
            const float bs = bias[col];
            #pragma unroll
            for (int r = 0; r < 4; ++r)
                Cf[(size_t)(row + r) * 1024 + col] = v[r] + bs;
        }
    }
}

// ======================= flash attention (unchanged) ================
__global__ __launch_bounds__(256, 4) void attn_fwd(
    const bf16* __restrict__ Q, const bf16* __restrict__ K,
    const bf16* __restrict__ Vt, bf16* __restrict__ O)
{
    __shared__ bf16 Kl[2][2][64][32];
    __shared__ bf16 Vl[2][2][64][32];

    const int tid = threadIdx.x, lane = tid & 63, wid = tid >> 6;
    int bid = blockIdx.x;
    const int h = bid & 15; bid >>= 4;
    const int qt = bid % 44, b = bid / 44;
    const int chunk = qt < 28 ? (qt >> 2) : 7;
    const int qrow0 = b * (TOUT * S_) +
                      (qt < 28 ? chunk * S_ + (qt & 3) * 64 : 7 * S_ + (qt - 28) * 64);

    const bf16* kg = K  + ((size_t)(b * 8 + chunk) * KVL) * 1024 + h * 64;
    const bf16* vg = Vt + ((size_t)((b * 8 + chunk) * 16 + h)) * 64 * KVL;

    const int l15 = lane & 15, l4 = lane >> 4;

    const bf16* qp = Q + (size_t)(qrow0 + wid * 16 + l15) * D_ + h * 64 + l4 * 8;
    u32x4 q0, q1;
    {
        bf16x8 t0 = *(const bf16x8*)qp;
        bf16x8 t1 = *(const bf16x8*)(qp + 32);
        #pragma unroll
        for (int j = 0; j < 8; ++j) {
            t0[j] = (bf16)((float)t0[j] * 0.125f);
            t1[j] = (bf16)((float)t1[j] * 0.125f);
        }
        q0 = __builtin_bit_cast(u32x4, t0);
        q1 = __builtin_bit_cast(u32x4, t1);
    }

    const int R   = wid * 16 + (lane >> 2);
    const int gsw = ((lane & 3) ^ ((lane >> 3) & 3)) * 8;
    const int rg  = (l4 ^ ((l15 >> 1) & 3)) * 8;

    const int baseA = ((2 * (l4 & 1)) * 16 + l15) * 4;
    const int baseB = baseA + 64;
    const bool hi2 = (l4 & 2) != 0;

    float m_s = -1e30f, l_s = 0.f;
    f32x4 oacc[4];
    const f32x4 zf = {0.f, 0.f, 0.f, 0.f};
    #pragma unroll
    for (int m2 = 0; m2 < 4; ++m2) oacc[m2] = zf;

#define ASTAGE(c, t) do { \
    const int kv0_ = (t) * 64; \
    gload_lds16(kg + (size_t)(kv0_ + R) * 1024 + gsw,      &Kl[c][0][0][0] + wid * 512); \
    gload_lds16(kg + (size_t)(kv0_ + R) * 1024 + 32 + gsw, &Kl[c][1][0][0] + wid * 512); \
    gload_lds16(vg + (size_t)R * KVL + kv0_ + gsw,         &Vl[c][0][0][0] + wid * 512); \
    gload_lds16(vg + (size_t)R * KVL + kv0_ + 32 + gsw,    &Vl[c][1][0][0] + wid * 512); \
} while (0)

    ASTAGE(0, 0);
    __syncthreads();

    #pragma unroll 1
    for (int kt = 0; kt < 12; ++kt) {
        const int cur = kt & 1;
        if (kt < 11) ASTAGE(cur ^ 1, kt + 1);

        f32x4 s[4];
        #pragma unroll
        for (int n = 0; n < 4; ++n) {
            const bf16* kp = &Kl[cur][0][n * 16 + l15][0] + rg;
            const u32x4 k0 = *(const u32x4*)kp;
            const u32x4 k1 = *(const u32x4*)(kp + 2048);
            f32x4 t = mfma16(as_bf(k0), as_bf(q0), zf);
            s[n] = mfma16(as_bf(k1), as_bf(q1), t);
        }

        float pm = s[0][0];
        #pragma unroll
        for (int n = 0; n < 4; ++n)
            #pragma unroll
            for (int r = 0; r < 4; ++r) pm = fmaxf(pm, s[n][r]);
        pm = fmaxf(pm, __shfl_xor(pm, 16));
        pm = fmaxf(pm, __shfl_xor(pm, 32));
        const float mn = fmaxf(m_s, pm);
        const float al = __expf(m_s - mn);
        m_s = mn;
        float p[4][4];
        float sum = 0.f;
        #pragma unroll
        for (int n = 0; n < 4; ++n)
            #pragma unroll
            for (int r = 0; r < 4; ++r) {
                const float e = __expf(s[n][r] - mn);
                p[n][r] = e; sum += e;
            }
        sum += __shfl_xor(sum, 16);
        sum += __shfl_xor(sum, 32);
        l_s = l_s * al + sum;
        #pragma unroll
        for (int m2 = 0; m2 < 4; ++m2) oacc[m2] *= al;

        int u[4][2];
        #pragma unroll
        for (int n = 0; n < 4; ++n) {
            u[n][0] = cvtpk(p[n][0], p[n][1]);
            u[n][1] = cvtpk(p[n][2], p[n][3]);
        }

        #pragma unroll
        for (int kk = 0; kk < 2; ++kk) {
            const int e0 = __builtin_amdgcn_ds_bpermute(baseA, u[2 * kk][0]);
            const int f0 = __builtin_amdgcn_ds_bpermute(baseA, u[2 * kk + 1][0]);
            const int e1 = __builtin_amdgcn_ds_bpermute(baseA, u[2 * kk][1]);
            const int f1 = __builtin_amdgcn_ds_bpermute(baseA, u[2 * kk + 1][1]);
            const int e2 = __builtin_amdgcn_ds_bpermute(baseB, u[2 * kk][0]);
            const int f2 = __builtin_amdgcn_ds_bpermute(baseB, u[2 * kk + 1][0]);
            const int e3 = __builtin_amdgcn_ds_bpermute(baseB, u[2 * kk][1]);
            const int f3 = __builtin_amdgcn_ds_bpermute(baseB, u[2 * kk + 1][1]);
            u32x4 pb;
            pb[0] = (unsigned)(hi2 ? f0 : e0);
            pb[1] = (unsigned)(hi2 ? f1 : e1);
            pb[2] = (unsigned)(hi2 ? f2 : e2);
            pb[3] = (unsigned)(hi2 ? f3 : e3);
            #pragma unroll
            for (int m2 = 0; m2 < 4; ++m2) {
                const u32x4 vf = *(const u32x4*)(&Vl[cur][kk][m2 * 16 + l15][0] + rg);
                oacc[m2] = mfma16(as_bf(vf), as_bf(pb), oacc[m2]);
            }
        }
        __syncthreads();
    }
#undef ASTAGE

    const float inv = 1.f / l_s;
    bf16* sc = &Kl[0][0][0][0] + wid * 1152;
    #pragma unroll
    for (int m2 = 0; m2 < 4; ++m2)
        #pragma unroll
        for (int r = 0; r < 4; ++r)
            sc[l15 * 72 + m2 * 16 + l4 * 4 + r] = (bf16)(oacc[m2][r] * inv);
    const int rq = lane >> 2, rd = (lane & 3) * 16;
    const bf16* sr = sc + rq * 72 + rd;
    const u32x4 o0 = *(const u32x4*)sr;
    const u32x4 o1 = *(const u32x4*)(sr + 8);
    bf16* op = O + (size_t)(qrow0 + wid * 16 + rq) * D_ + h * 64 + rd;
    *(u32x4*)op = o0;
    *(u32x4*)(op + 8) = o1;
}

// ======================= launch =====================================
extern "C" void kernel_launch(void* const* d_in, const int* in_sizes, int n_in,
                              void* d_out, int out_size, void* d_ws, size_t ws_size,
                              hipStream_t stream) {
    (void)in_sizes; (void)n_in; (void)out_size; (void)ws_size;
    const float* x    = (const float*)d_in[0];
    const float* Wqkv = (const float*)d_in[1];
    const float* Wout = (const float*)d_in[2];
    const float* bout = (const float*)d_in[3];

    bf16* Aq     = (bf16*)d_ws;
    bf16* Akv    = Aq     + (size_t)MQ  * 1024;
    bf16* Wqkv_t = Akv    + (size_t)MKV * 1024;
    bf16* Wout_t = Wqkv_t + (size_t)3072 * 1024;
    bf16* Qb     = Wout_t + (size_t)1024 * 1024;
    bf16* Kb     = Qb     + (size_t)MQ  * 1024;
    bf16* Vtb    = Kb     + (size_t)MKV * 1024;
    bf16* Ob     = Aq;

    prep<<<PB_TOT, 256, 0, stream>>>(x, Wqkv, Wout, Aq, Akv, Wqkv_t, Wout_t);

    gemm_qkv<<<944, 512, 0, stream>>>(Aq, Akv, Wqkv_t, Qb, Kb, Vtb);

    attn_fwd<<<4 * 44 * 16, 256, 0, stream>>>(Qb, Kb, Vtb, Ob);

    gemm_out<<<176, 512, 0, stream>>>(Ob, Wout_t, (float*)d_out, bout);
}

// Round 7
// 309.438 us; speedup vs baseline: 1.0028x; 1.0028x over previous
//
// MemFullAttention_19585050870313 — MI355X round 5
// Change vs round 4: GEMM phase schedule rebuilt as read-prefetch-balanced:
//   - exactly 6 ds_read_b128 per phase (was 12/4/8/0) -> LDS pipe 576 cyc/phase < MFMA 620
//   - reads issued one phase EARLY (post-MM), double-buffered regs aX/aY/bP/bQ
//   - vmcnt(6) at every phase end (global stage-landing guard, distance-4 proof)
// prep / attn_fwd unchanged from round 4.
#include <hip/hip_runtime.h>
#include <hip/hip_bf16.h>

typedef __bf16 bf16;
typedef __bf16 bf16x8 __attribute__((ext_vector_type(8)));
typedef float  f32x4  __attribute__((ext_vector_type(4)));
typedef float  f32x4v __attribute__((ext_vector_type(4)));
typedef unsigned int u32x4 __attribute__((ext_vector_type(4)));
typedef unsigned short u16x4 __attribute__((ext_vector_type(4)));

#define DEV __device__ __forceinline__

DEV void gload_lds16(const bf16* g, bf16* l) {
    __builtin_amdgcn_global_load_lds(
        (__attribute__((address_space(1))) void*)g,
        (__attribute__((address_space(3))) void*)l, 16, 0, 0);
}

DEV bf16x8 as_bf(u32x4 v) { return __builtin_bit_cast(bf16x8, v); }

DEV f32x4 mfma16(bf16x8 a, bf16x8 b, f32x4 c) {
    return __builtin_amdgcn_mfma_f32_16x16x32_bf16(a, b, c, 0, 0, 0);
}

DEV int cvtpk(float lo, float hi) {
    int r;
    asm("v_cvt_pk_bf16_f32 %0, %1, %2" : "=v"(r) : "v"(lo), "v"(hi));
    return r;
}

// ---- problem constants (reference_length fixed at 3) ----
constexpr int D_   = 1024;
constexpr int S_   = 256;
constexpr int TOUT = 11;
constexpr int MQ   = 4 * TOUT * S_;   // 11264
constexpr int MKV  = 4 * 8 * 3 * S_;  // 24576
constexpr int KVL  = 768;

constexpr int PB_WQKV = 768;
constexpr int PB_WOUT = 256;
constexpr int PB_GQ   = MQ  * 128 / 256;     // 5632
constexpr int PB_GKV  = MKV * 128 / 256;     // 12288
constexpr int PB_TOT  = PB_WQKV + PB_WOUT + PB_GQ + PB_GKV;

// ======================= fused prep (unchanged) =====================
__global__ void prep(const float* __restrict__ x,
                     const float* __restrict__ Wqkv,
                     const float* __restrict__ Wout,
                     bf16* __restrict__ Aq, bf16* __restrict__ Akv,
                     bf16* __restrict__ Wqkv_t, bf16* __restrict__ Wout_t)
{
    __shared__ float T[64][65];
    const int tid = threadIdx.x;
    int wg = blockIdx.x;

    if (wg < PB_WQKV + PB_WOUT) {
        const float* W; bf16* Wt; int N, bid2;
        if (wg < PB_WQKV) { W = Wqkv; Wt = Wqkv_t; N = 3072; bid2 = wg; }
        else              { W = Wout; Wt = Wout_t; N = 1024; bid2 = wg - PB_WQKV; }
        const int kt = bid2 & 15, nt = bid2 >> 4;
        const int k0 = kt * 64, n0 = nt * 64;
        for (int i = 0; i < 16; ++i) {
            const int e = i * 256 + tid;
            const int kk = e >> 6, nn = e & 63;
            T[nn][kk] = W[(size_t)(k0 + kk) * N + n0 + nn];
        }
        __syncthreads();
        for (int i = 0; i < 16; ++i) {
            const int e = i * 256 + tid;
            const int n = e >> 6, kk = e & 63;
            Wt[(size_t)(n0 + n) * 1024 + k0 + kk] = (bf16)T[n][kk];
        }
        return;
    }
    wg -= PB_WQKV + PB_WOUT;

    int row, part;
    const float* src;
    bf16* dst;
    if (wg < PB_GQ) {
        const int idx = wg * 256 + tid;
        row = idx >> 7; part = idx & 127;
        const int b    = row / (TOUT * S_);
        const int r2   = row - b * (TOUT * S_);
        const int tout = r2 >> 8;
        const int s    = r2 & 255;
        const int tx   = tout < 7 ? tout * 4 : 28 + (tout - 7);
        src = x + ((size_t)((b * 32 + tx) * S_ + s)) * D_ + part * 8;
        dst = Aq + (size_t)row * D_ + part * 8;
    } else {
        const int idx = (wg - PB_GQ) * 256 + tid;
        row = idx >> 7; part = idx & 127;
        const int b  = row / 6144;
        const int r2 = row - b * 6144;
        const int c  = r2 / KVL;
        const int j  = r2 - c * KVL;
        const int f  = 1 + (j >> 8);
        const int s  = j & 255;
        const int tx = c * 4 + f;
        src = x + ((size_t)((b * 32 + tx) * S_ + s)) * D_ + part * 8;
        dst = Akv + (size_t)row * D_ + part * 8;
    }
    f32x4v v0 = *(const f32x4v*)src;
    f32x4v v1 = *(const f32x4v*)(src + 4);
    bf16x8 o;
    o[0]=(bf16)v0[0]; o[1]=(bf16)v0[1]; o[2]=(bf16)v0[2]; o[3]=(bf16)v0[3];
    o[4]=(bf16)v1[0]; o[5]=(bf16)v1[1]; o[6]=(bf16)v1[2]; o[7]=(bf16)v1[3];
    *(bf16x8*)dst = o;
}

// ======================= 8-phase GEMM, balanced read-prefetch =======
#define PH_BEGIN() do { \
    __builtin_amdgcn_s_barrier(); \
    asm volatile("s_waitcnt lgkmcnt(0)" ::: "memory"); \
    __builtin_amdgcn_sched_barrier(0); \
    __builtin_amdgcn_s_setprio(1); \
} while(0)

#define PH_MMEND() do { \
    __builtin_amdgcn_s_setprio(0); \
    __builtin_amdgcn_sched_barrier(0); \
} while(0)

#define PH_CLOSE() do { \
    asm volatile("s_waitcnt vmcnt(6)" ::: "memory"); \
    __builtin_amdgcn_s_barrier(); \
} while(0)

#define STAGE_A(bufc, half, tile) do { \
    const bf16* s0_ = pA + (size_t)(half) * 64 * 1024 + (tile) * 64; \
    bf16* d0_ = ldsA + (bufc) * 16384 + (half) * 8192; \
    gload_lds16(s0_, d0_); \
    gload_lds16(s0_ + (size_t)128 * 1024, d0_ + 4096); \
} while(0)

#define STAGE_B(bufc, half, tile) do { \
    const bf16* s0_ = pB + (size_t)(half) * 32 * 1024 + (tile) * 64; \
    bf16* d0_ = ldsB + (bufc) * 16384 + (half) * 8192; \
    gload_lds16(s0_, d0_); \
    gload_lds16(s0_ + (size_t)128 * 1024, d0_ + 4096); \
} while(0)

// 2 ds_read_b128: one A j-frag (both k-slices)
#define LDAJ(dst, bufc, mh, J) do { \
    const bf16* p_ = sm + (bufc) * 16384 + (mh) * 8192 + (J) * 1024; \
    dst[J][0] = *(const u32x4*)(p_ + eA0); \
    dst[J][1] = *(const u32x4*)(p_ + eA1); \
} while(0)

// 4 ds_read_b128: both B i-frags of one half
#define LDBH(dst, bufc, nh) do { \
    const bf16* p_ = sm + 32768 + (bufc) * 16384 + (nh) * 8192; \
    dst[0][0] = *(const u32x4*)(p_ + eB0); \
    dst[0][1] = *(const u32x4*)(p_ + eB1); \
    dst[1][0] = *(const u32x4*)(p_ + 1024 + eB0); \
    dst[1][1] = *(const u32x4*)(p_ + 1024 + eB1); \
} while(0)

#define MMX(av, bv, mh, nh) do { \
    _Pragma("unroll") \
    for (int j_ = 0; j_ < 4; ++j_) { \
        _Pragma("unroll") \
        for (int i_ = 0; i_ < 2; ++i_) { \
            f32x4 c_ = acc[(mh)*4 + j_][(nh)*2 + i_]; \
            c_ = mfma16(as_bf(av[j_][0]), as_bf(bv[i_][0]), c_); \
            c_ = mfma16(as_bf(av[j_][1]), as_bf(bv[i_][1]), c_); \
            acc[(mh)*4 + j_][(nh)*2 + i_] = c_; \
        } \
    } \
} while(0)

// Schedule (per iter t: buf0=tile 2t, buf1=2t+1; stages n0=2t+2, n1=2t+3):
//  ph1 stage A1h1(2t+1) | MM(aX,bP,0,0) | read bQ(0,1)+aY(0,1,j0)
//  ph2 stage A0h0(n0)   | MM(aX,bQ,0,1) | read aY(0,1,j1..3)
//  ph3 stage B0h0(n0)   | MM(aY,bP,1,0) | read aX(1,0,j0..2)
//  ph4 stage B0h1(n0)   | MM(aY,bQ,1,1) | read aX(1,0,j3)+bP(1,0)
//  ph5 stage A0h1(n0)   | MM(aX,bP,0,0) | read bQ(1,1)+aY(1,1,j0)
//  ph6 stage A1h0(n1)   | MM(aX,bQ,0,1) | read aY(1,1,j1..3)
//  ph7 stage B1h0(n1)   | MM(aY,bP,1,0) | read aX(0,0,j0..2)'
//  ph8 stage B1h1(n1)   | MM(aY,bQ,1,1) | read aX(0,0,j3)'+bP(0,0)'
// Every read's stage-distance >= 4 (guarded by per-phase vmcnt(6)+barrier);
// every stage's slot had its last reg-read >= 2 phases earlier.
#define GEMM_MAINLOOP() do { \
    STAGE_A(0, 0, 0); STAGE_A(0, 1, 0); STAGE_B(0, 0, 0); STAGE_B(0, 1, 0); \
    STAGE_A(1, 0, 1); STAGE_B(1, 0, 1); STAGE_B(1, 1, 1); \
    asm volatile("s_waitcnt vmcnt(6)" ::: "memory"); \
    __builtin_amdgcn_s_barrier(); \
    LDAJ(aX,0,0,0); LDAJ(aX,0,0,1); LDAJ(aX,0,0,2); LDAJ(aX,0,0,3); \
    LDBH(bP,0,0); \
    _Pragma("unroll 1") \
    for (int t = 0; t < 8; ++t) { \
        const int T1 = 2 * t + 1; \
        const int n0 = (2 * t + 2 < 15) ? 2 * t + 2 : 15; \
        const int n1 = (2 * t + 3 < 15) ? 2 * t + 3 : 15; \
        STAGE_A(1, 1, T1); \
        PH_BEGIN(); MMX(aX, bP, 0, 0); PH_MMEND(); \
        LDBH(bQ, 0, 1); LDAJ(aY, 0, 1, 0); \
        PH_CLOSE(); \
        STAGE_A(0, 0, n0); \
        PH_BEGIN(); MMX(aX, bQ, 0, 1); PH_MMEND(); \
        LDAJ(aY, 0, 1, 1); LDAJ(aY, 0, 1, 2); LDAJ(aY, 0, 1, 3); \
        PH_CLOSE(); \
        STAGE_B(0, 0, n0); \
        PH_BEGIN(); MMX(aY, bP, 1, 0); PH_MMEND(); \
        LDAJ(aX, 1, 0, 0); LDAJ(aX, 1, 0, 1); LDAJ(aX, 1, 0, 2); \
        PH_CLOSE(); \
        STAGE_B(0, 1, n0); \
        PH_BEGIN(); MMX(aY, bQ, 1, 1); PH_MMEND(); \
        LDAJ(aX, 1, 0, 3); LDBH(bP, 1, 0); \
        PH_CLOSE(); \
        STAGE_A(0, 1, n0); \
        PH_BEGIN(); MMX(aX, bP, 0, 0); PH_MMEND(); \
        LDBH(bQ, 1, 1); LDAJ(aY, 1, 1, 0); \
        PH_CLOSE(); \
        STAGE_A(1, 0, n1); \
        PH_BEGIN(); MMX(aX, bQ, 0, 1); PH_MMEND(); \
        LDAJ(aY, 1, 1, 1); LDAJ(aY, 1, 1, 2); LDAJ(aY, 1, 1, 3); \
        PH_CLOSE(); \
        STAGE_B(1, 0, n1); \
        PH_BEGIN(); MMX(aY, bP, 1, 0); PH_MMEND(); \
        LDAJ(aX, 0, 0, 0); LDAJ(aX, 0, 0, 1); LDAJ(aX, 0, 0, 2); \
        PH_CLOSE(); \
        STAGE_B(1, 1, n1); \
        PH_BEGIN(); MMX(aY, bQ, 1, 1); PH_MMEND(); \
        LDAJ(aX, 0, 0, 3); LDBH(bP, 0, 0); \
        PH_CLOSE(); \
    } \
    asm volatile("s_waitcnt vmcnt(0) lgkmcnt(0)" ::: "memory"); \
} while(0)

#define GEMM_PREAMBLE() \
    const int wr = wid >> 2, wc = wid & 3; \
    const int l15 = lane & 15, l4 = lane >> 4; \
    const int Rrow = (wid << 3) + (lane >> 3); \
    const int G    = (lane & 7) ^ (lane >> 3); \
    const bf16* pA = A  + (size_t)(bm * 256 + Rrow) * 1024 + G * 8; \
    const int wc1 = Rrow >> 5, cc1 = Rrow & 31; \
    const bf16* pB = Bt + (size_t)(bn * 256 + wc1 * 64 + cc1) * 1024 + G * 8; \
    bf16* ldsA = sm + (wid << 9); \
    bf16* ldsB = sm + 32768 + (wid << 9); \
    const int g0  = l4 ^ (l15 & 7); \
    const int eA0 = wr * 4096 + l15 * 64 + g0 * 8; \
    const int eA1 = eA0 ^ 32; \
    const int eB0 = wc * 2048 + l15 * 64 + g0 * 8; \
    const int eB1 = eB0 ^ 32; \
    f32x4 acc[8][4]; \
    u32x4 aX[4][2], aY[4][2], bP[2][2], bQ[2][2]; \
    { const f32x4 zf_ = {0.f, 0.f, 0.f, 0.f}; \
      _Pragma("unroll") \
      for (int m_ = 0; m_ < 8; ++m_) \
          _Pragma("unroll") \
          for (int n_ = 0; n_ < 4; ++n_) acc[m_][n_] = zf_; }

// ======================= fused Q+KV projection GEMM =================
__global__ __launch_bounds__(512, 2) void gemm_qkv(
    const bf16* __restrict__ Aq, const bf16* __restrict__ Akv,
    const bf16* __restrict__ Wt,
    bf16* __restrict__ Qb, bf16* __restrict__ Kb, bf16* __restrict__ Vt)
{
    __shared__ bf16 sm[65536];
    const int tid = threadIdx.x, lane = tid & 63, wid = tid >> 6;

    int wg = blockIdx.x;
    {   // bijective XCD swizzle, nwg=944
        const int xcd = wg & 7, off = wg >> 3;
        wg = xcd * 118 + off;
    }
    const bool isQ = wg < 176;
    const bf16* A;  const bf16* Bt;  int bm, bn;
    if (isQ) { A = Aq;  Bt = Wt;                       bm = wg % 44;  bn = wg / 44; }
    else     { wg -= 176;
               A = Akv; Bt = Wt + (size_t)1024 * 1024; bm = wg % 96;  bn = wg / 96; }

    GEMM_PREAMBLE();
    GEMM_MAINLOOP();

    if (isQ || bn < 4) {
        bf16* C = isQ ? Qb : Kb;
        #pragma unroll
        for (int m = 0; m < 8; ++m) {
            const int row = bm * 256 + wr * 128 + m * 16 + l4 * 4;
            #pragma unroll
            for (int n = 0; n < 4; ++n) {
                const int col = bn * 256 + wc * 64 + n * 16 + l15;
                f32x4 v = acc[m][n];
                #pragma unroll
                for (int r = 0; r < 4; ++r)
                    C[(size_t)(row + r) * 1024 + col] = (bf16)v[r];
            }
        }
    } else {
        const int vb = bm / 3;
        const int j0base = (bm % 3) * 256;
        #pragma unroll
        for (int m = 0; m < 8; ++m) {
            const int j0 = j0base + wr * 128 + m * 16 + l4 * 4;
            #pragma unroll
            for (int n = 0; n < 4; ++n) {
                const int colv = (bn - 4) * 256 + wc * 64 + n * 16 + l15;
                f32x4 v = acc[m][n];
                u16x4 pk;
                #pragma unroll
                for (int r = 0; r < 4; ++r) {
                    bf16 t = (bf16)v[r];
                    pk[r] = __builtin_bit_cast(unsigned short, t);
                }
                *(u16x4*)(Vt + ((size_t)vb * 1024 + colv) * KVL + j0) = pk;
            }
        }
    }
}

// ======================= out GEMM ===================================
__global__ __launch_bounds__(512, 2) void gemm_out(
    const bf16* __restrict__ A, const bf16* __restrict__ Bt,
    float* __restrict__ Cf, const float* __restrict__ bias)
{
    __shared__ bf16 sm[65536];
    const int tid = threadIdx.x, lane = tid & 63, wid = tid >> 6;

    int wg = blockIdx.x;
    {   // nwg=176: q=22
        const int xcd = wg & 7, off = wg >> 3;
        wg = xcd * 22 + off;
    }
    const int bm = wg % 44, bn = wg / 44;

    GEMM_PREAMBLE();
    GEMM_MAINLOOP();

    #pragma unroll
    for (int m = 0; m < 8; ++m) {
        const int row = bm * 256 + wr * 128 + m * 16 + l4 * 4;
        #pragma unroll
        for (int n = 0; n < 4; ++n) {
            const int col = bn * 256 + wc * 64 + n * 16 + l15;
            f32x4 v = acc[m][n];
            const float bs = bias[col];
            #pragma unroll
            for (int r = 0; r < 4; ++r)
                Cf[(size_t)(row + r) * 1024 + col] = v[r] + bs;
        }
    }
}

// ======================= flash attention (unchanged) ================
__global__ __launch_bounds__(256, 4) void attn_fwd(
    const bf16* __restrict__ Q, const bf16* __restrict__ K,
    const bf16* __restrict__ Vt, bf16* __restrict__ O)
{
    __shared__ bf16 Kl[2][2][64][32];
    __shared__ bf16 Vl[2][2][64][32];

    const int tid = threadIdx.x, lane = tid & 63, wid = tid >> 6;
    int bid = blockIdx.x;
    const int h = bid & 15; bid >>= 4;
    const int qt = bid % 44, b = bid / 44;
    const int chunk = qt < 28 ? (qt >> 2) : 7;
    const int qrow0 = b * (TOUT * S_) +
                      (qt < 28 ? chunk * S_ + (qt & 3) * 64 : 7 * S_ + (qt - 28) * 64);

    const bf16* kg = K  + ((size_t)(b * 8 + chunk) * KVL) * 1024 + h * 64;
    const bf16* vg = Vt + ((size_t)((b * 8 + chunk) * 16 + h)) * 64 * KVL;

    const int l15 = lane & 15, l4 = lane >> 4;

    const bf16* qp = Q + (size_t)(qrow0 + wid * 16 + l15) * D_ + h * 64 + l4 * 8;
    u32x4 q0, q1;
    {
        bf16x8 t0 = *(const bf16x8*)qp;
        bf16x8 t1 = *(const bf16x8*)(qp + 32);
        #pragma unroll
        for (int j = 0; j < 8; ++j) {
            t0[j] = (bf16)((float)t0[j] * 0.125f);
            t1[j] = (bf16)((float)t1[j] * 0.125f);
        }
        q0 = __builtin_bit_cast(u32x4, t0);
        q1 = __builtin_bit_cast(u32x4, t1);
    }

    const int R   = wid * 16 + (lane >> 2);
    const int gsw = ((lane & 3) ^ ((lane >> 3) & 3)) * 8;
    const int rg  = (l4 ^ ((l15 >> 1) & 3)) * 8;

    const int baseA = ((2 * (l4 & 1)) * 16 + l15) * 4;
    const int baseB = baseA + 64;
    const bool hi2 = (l4 & 2) != 0;

    float m_s = -1e30f, l_s = 0.f;
    f32x4 oacc[4];
    const f32x4 zf = {0.f, 0.f, 0.f, 0.f};
    #pragma unroll
    for (int m2 = 0; m2 < 4; ++m2) oacc[m2] = zf;

#define ASTAGE(c, t) do { \
    const int kv0_ = (t) * 64; \
    gload_lds16(kg + (size_t)(kv0_ + R) * 1024 + gsw,      &Kl[c][0][0][0] + wid * 512); \
    gload_lds16(kg + (size_t)(kv0_ + R) * 1024 + 32 + gsw, &Kl[c][1][0][0] + wid * 512); \
    gload_lds16(vg + (size_t)R * KVL + kv0_ + gsw,         &Vl[c][0][0][0] + wid * 512); \
    gload_lds16(vg + (size_t)R * KVL + kv0_ + 32 + gsw,    &Vl[c][1][0][0] + wid * 512); \
} while (0)

    ASTAGE(0, 0);
    __syncthreads();

    #pragma unroll 1
    for (int kt = 0; kt < 12; ++kt) {
        const int cur = kt & 1;
        if (kt < 11) ASTAGE(cur ^ 1, kt + 1);

        f32x4 s[4];
        #pragma unroll
        for (int n = 0; n < 4; ++n) {
            const bf16* kp = &Kl[cur][0][n * 16 + l15][0] + rg;
            const u32x4 k0 = *(const u32x4*)kp;
            const u32x4 k1 = *(const u32x4*)(kp + 2048);
            f32x4 t = mfma16(as_bf(k0), as_bf(q0), zf);
            s[n] = mfma16(as_bf(k1), as_bf(q1), t);
        }

        float pm = s[0][0];
        #pragma unroll
        for (int n = 0; n < 4; ++n)
            #pragma unroll
            for (int r = 0; r < 4; ++r) pm = fmaxf(pm, s[n][r]);
        pm = fmaxf(pm, __shfl_xor(pm, 16));
        pm = fmaxf(pm, __shfl_xor(pm, 32));
        const float mn = fmaxf(m_s, pm);
        const float al = __expf(m_s - mn);
        m_s = mn;
        float p[4][4];
        float sum = 0.f;
        #pragma unroll
        for (int n = 0; n < 4; ++n)
            #pragma unroll
            for (int r = 0; r < 4; ++r) {
                const float e = __expf(s[n][r] - mn);
                p[n][r] = e; sum += e;
            }
        sum += __shfl_xor(sum, 16);
        sum += __shfl_xor(sum, 32);
        l_s = l_s * al + sum;
        #pragma unroll
        for (int m2 = 0; m2 < 4; ++m2) oacc[m2] *= al;

        int u[4][2];
        #pragma unroll
        for (int n = 0; n < 4; ++n) {
            u[n][0] = cvtpk(p[n][0], p[n][1]);
            u[n][1] = cvtpk(p[n][2], p[n][3]);
        }

        #pragma unroll
        for (int kk = 0; kk < 2; ++kk) {
            const int e0 = __builtin_amdgcn_ds_bpermute(baseA, u[2 * kk][0]);
            const int f0 = __builtin_amdgcn_ds_bpermute(baseA, u[2 * kk + 1][0]);
            const int e1 = __builtin_amdgcn_ds_bpermute(baseA, u[2 * kk][1]);
            const int f1 = __builtin_amdgcn_ds_bpermute(baseA, u[2 * kk + 1][1]);
            const int e2 = __builtin_amdgcn_ds_bpermute(baseB, u[2 * kk][0]);
            const int f2 = __builtin_amdgcn_ds_bpermute(baseB, u[2 * kk + 1][0]);
            const int e3 = __builtin_amdgcn_ds_bpermute(baseB, u[2 * kk][1]);
            const int f3 = __builtin_amdgcn_ds_bpermute(baseB, u[2 * kk + 1][1]);
            u32x4 pb;
            pb[0] = (unsigned)(hi2 ? f0 : e0);
            pb[1] = (unsigned)(hi2 ? f1 : e1);
            pb[2] = (unsigned)(hi2 ? f2 : e2);
            pb[3] = (unsigned)(hi2 ? f3 : e3);
            #pragma unroll
            for (int m2 = 0; m2 < 4; ++m2) {
                const u32x4 vf = *(const u32x4*)(&Vl[cur][kk][m2 * 16 + l15][0] + rg);
                oacc[m2] = mfma16(as_bf(vf), as_bf(pb), oacc[m2]);
            }
        }
        __syncthreads();
    }
#undef ASTAGE

    const float inv = 1.f / l_s;
    bf16* sc = &Kl[0][0][0][0] + wid * 1152;
    #pragma unroll
    for (int m2 = 0; m2 < 4; ++m2)
        #pragma unroll
        for (int r = 0; r < 4; ++r)
            sc[l15 * 72 + m2 * 16 + l4 * 4 + r] = (bf16)(oacc[m2][r] * inv);
    const int rq = lane >> 2, rd = (lane & 3) * 16;
    const bf16* sr = sc + rq * 72 + rd;
    const u32x4 o0 = *(const u32x4*)sr;
    const u32x4 o1 = *(const u32x4*)(sr + 8);
    bf16* op = O + (size_t)(qrow0 + wid * 16 + rq) * D_ + h * 64 + rd;
    *(u32x4*)op = o0;
    *(u32x4*)(op + 8) = o1;
}

// ======================= launch =====================================
extern "C" void kernel_launch(void* const* d_in, const int* in_sizes, int n_in,
                              void* d_out, int out_size, void* d_ws, size_t ws_size,
                              hipStream_t stream) {
    (void)in_sizes; (void)n_in; (void)out_size; (void)ws_size;
    const float* x    = (const float*)d_in[0];
    const float* Wqkv = (const float*)d_in[1];
    const float* Wout = (const float*)d_in[2];
    const float* bout = (const float*)d_in[3];

    bf16* Aq     = (bf16*)d_ws;
    bf16* Akv    = Aq     + (size_t)MQ  * 1024;
    bf16* Wqkv_t = Akv    + (size_t)MKV * 1024;
    bf16* Wout_t = Wqkv_t + (size_t)3072 * 1024;
    bf16* Qb     = Wout_t + (size_t)1024 * 1024;
    bf16* Kb     = Qb     + (size_t)MQ  * 1024;
    bf16* Vtb    = Kb     + (size_t)MKV * 1024;
    bf16* Ob     = Aq;

    prep<<<PB_TOT, 256, 0, stream>>>(x, Wqkv, Wout, Aq, Akv, Wqkv_t, Wout_t);

    gemm_qkv<<<944, 512, 0, stream>>>(Aq, Akv, Wqkv_t, Qb, Kb, Vtb);

    attn_fwd<<<4 * 44 * 16, 256, 0, stream>>>(Qb, Kb, Vtb, Ob);

    gemm_out<<<176, 512, 0, stream>>>(Ob, Wout_t, (float*)d_out, bout);
}

// Round 8
// 308.514 us; speedup vs baseline: 1.0058x; 1.0030x over previous
//
// MemFullAttention_19585050870313 — MI355X round 5
// Change vs round 4: GEMM phase schedule rebuilt as read-prefetch-balanced:
//   - exactly 6 ds_read_b128 per phase (was 12/4/8/0) -> LDS pipe 576 cyc/phase < MFMA 620
//   - reads issued one phase EARLY (post-MM), double-buffered regs aX/aY/bP/bQ
//   - vmcnt(6) at every phase end (global stage-landing guard, distance-4 proof)
// prep / attn_fwd unchanged from round 4.
#include <hip/hip_runtime.h>
#include <hip/hip_bf16.h>

typedef __bf16 bf16;
typedef __bf16 bf16x8 __attribute__((ext_vector_type(8)));
typedef float  f32x4  __attribute__((ext_vector_type(4)));
typedef float  f32x4v __attribute__((ext_vector_type(4)));
typedef unsigned int u32x4 __attribute__((ext_vector_type(4)));
typedef unsigned short u16x4 __attribute__((ext_vector_type(4)));

#define DEV __device__ __forceinline__

DEV void gload_lds16(const bf16* g, bf16* l) {
    __builtin_amdgcn_global_load_lds(
        (__attribute__((address_space(1))) void*)g,
        (__attribute__((address_space(3))) void*)l, 16, 0, 0);
}

DEV bf16x8 as_bf(u32x4 v) { return __builtin_bit_cast(bf16x8, v); }

DEV f32x4 mfma16(bf16x8 a, bf16x8 b, f32x4 c) {
    return __builtin_amdgcn_mfma_f32_16x16x32_bf16(a, b, c, 0, 0, 0);
}

DEV int cvtpk(float lo, float hi) {
    int r;
    asm("v_cvt_pk_bf16_f32 %0, %1, %2" : "=v"(r) : "v"(lo), "v"(hi));
    return r;
}

// ---- problem constants (reference_length fixed at 3) ----
constexpr int D_   = 1024;
constexpr int S_   = 256;
constexpr int TOUT = 11;
constexpr int MQ   = 4 * TOUT * S_;   // 11264
constexpr int MKV  = 4 * 8 * 3 * S_;  // 24576
constexpr int KVL  = 768;

constexpr int PB_WQKV = 768;
constexpr int PB_WOUT = 256;
constexpr int PB_GQ   = MQ  * 128 / 256;     // 5632
constexpr int PB_GKV  = MKV * 128 / 256;     // 12288
constexpr int PB_TOT  = PB_WQKV + PB_WOUT + PB_GQ + PB_GKV;

// ======================= fused prep (unchanged) =====================
__global__ void prep(const float* __restrict__ x,
                     const float* __restrict__ Wqkv,
                     const float* __restrict__ Wout,
                     bf16* __restrict__ Aq, bf16* __restrict__ Akv,
                     bf16* __restrict__ Wqkv_t, bf16* __restrict__ Wout_t)
{
    __shared__ float T[64][65];
    const int tid = threadIdx.x;
    int wg = blockIdx.x;

    if (wg < PB_WQKV + PB_WOUT) {
        const float* W; bf16* Wt; int N, bid2;
        if (wg < PB_WQKV) { W = Wqkv; Wt = Wqkv_t; N = 3072; bid2 = wg; }
        else              { W = Wout; Wt = Wout_t; N = 1024; bid2 = wg - PB_WQKV; }
        const int kt = bid2 & 15, nt = bid2 >> 4;
        const int k0 = kt * 64, n0 = nt * 64;
        for (int i = 0; i < 16; ++i) {
            const int e = i * 256 + tid;
            const int kk = e >> 6, nn = e & 63;
            T[nn][kk] = W[(size_t)(k0 + kk) * N + n0 + nn];
        }
        __syncthreads();
        for (int i = 0; i < 16; ++i) {
            const int e = i * 256 + tid;
            const int n = e >> 6, kk = e & 63;
            Wt[(size_t)(n0 + n) * 1024 + k0 + kk] = (bf16)T[n][kk];
        }
        return;
    }
    wg -= PB_WQKV + PB_WOUT;

    int row, part;
    const float* src;
    bf16* dst;
    if (wg < PB_GQ) {
        const int idx = wg * 256 + tid;
        row = idx >> 7; part = idx & 127;
        const int b    = row / (TOUT * S_);
        const int r2   = row - b * (TOUT * S_);
        const int tout = r2 >> 8;
        const int s    = r2 & 255;
        const int tx   = tout < 7 ? tout * 4 : 28 + (tout - 7);
        src = x + ((size_t)((b * 32 + tx) * S_ + s)) * D_ + part * 8;
        dst = Aq + (size_t)row * D_ + part * 8;
    } else {
        const int idx = (wg - PB_GQ) * 256 + tid;
        row = idx >> 7; part = idx & 127;
        const int b  = row / 6144;
        const int r2 = row - b * 6144;
        const int c  = r2 / KVL;
        const int j  = r2 - c * KVL;
        const int f  = 1 + (j >> 8);
        const int s  = j & 255;
        const int tx = c * 4 + f;
        src = x + ((size_t)((b * 32 + tx) * S_ + s)) * D_ + part * 8;
        dst = Akv + (size_t)row * D_ + part * 8;
    }
    f32x4v v0 = *(const f32x4v*)src;
    f32x4v v1 = *(const f32x4v*)(src + 4);
    bf16x8 o;
    o[0]=(bf16)v0[0]; o[1]=(bf16)v0[1]; o[2]=(bf16)v0[2]; o[3]=(bf16)v0[3];
    o[4]=(bf16)v1[0]; o[5]=(bf16)v1[1]; o[6]=(bf16)v1[2]; o[7]=(bf16)v1[3];
    *(bf16x8*)dst = o;
}

// ======================= 8-phase GEMM, balanced read-prefetch =======
#define PH_BEGIN() do { \
    __builtin_amdgcn_s_barrier(); \
    asm volatile("s_waitcnt lgkmcnt(0)" ::: "memory"); \
    __builtin_amdgcn_sched_barrier(0); \
    __builtin_amdgcn_s_setprio(1); \
} while(0)

#define PH_MMEND() do { \
    __builtin_amdgcn_s_setprio(0); \
    __builtin_amdgcn_sched_barrier(0); \
} while(0)

#define PH_CLOSE() do { \
    asm volatile("s_waitcnt vmcnt(6)" ::: "memory"); \
    __builtin_amdgcn_s_barrier(); \
} while(0)

#define STAGE_A(bufc, half, tile) do { \
    const bf16* s0_ = pA + (size_t)(half) * 64 * 1024 + (tile) * 64; \
    bf16* d0_ = ldsA + (bufc) * 16384 + (half) * 8192; \
    gload_lds16(s0_, d0_); \
    gload_lds16(s0_ + (size_t)128 * 1024, d0_ + 4096); \
} while(0)

#define STAGE_B(bufc, half, tile) do { \
    const bf16* s0_ = pB + (size_t)(half) * 32 * 1024 + (tile) * 64; \
    bf16* d0_ = ldsB + (bufc) * 16384 + (half) * 8192; \
    gload_lds16(s0_, d0_); \
    gload_lds16(s0_ + (size_t)128 * 1024, d0_ + 4096); \
} while(0)

// 2 ds_read_b128: one A j-frag (both k-slices)
#define LDAJ(dst, bufc, mh, J) do { \
    const bf16* p_ = sm + (bufc) * 16384 + (mh) * 8192 + (J) * 1024; \
    dst[J][0] = *(const u32x4*)(p_ + eA0); \
    dst[J][1] = *(const u32x4*)(p_ + eA1); \
} while(0)

// 4 ds_read_b128: both B i-frags of one half
#define LDBH(dst, bufc, nh) do { \
    const bf16* p_ = sm + 32768 + (bufc) * 16384 + (nh) * 8192; \
    dst[0][0] = *(const u32x4*)(p_ + eB0); \
    dst[0][1] = *(const u32x4*)(p_ + eB1); \
    dst[1][0] = *(const u32x4*)(p_ + 1024 + eB0); \
    dst[1][1] = *(const u32x4*)(p_ + 1024 + eB1); \
} while(0)

#define MMX(av, bv, mh, nh) do { \
    _Pragma("unroll") \
    for (int j_ = 0; j_ < 4; ++j_) { \
        _Pragma("unroll") \
        for (int i_ = 0; i_ < 2; ++i_) { \
            f32x4 c_ = acc[(mh)*4 + j_][(nh)*2 + i_]; \
            c_ = mfma16(as_bf(av[j_][0]), as_bf(bv[i_][0]), c_); \
            c_ = mfma16(as_bf(av[j_][1]), as_bf(bv[i_][1]), c_); \
            acc[(mh)*4 + j_][(nh)*2 + i_] = c_; \
        } \
    } \
} while(0)

// Schedule (per iter t: buf0=tile 2t, buf1=2t+1; stages n0=2t+2, n1=2t+3):
//  ph1 stage A1h1(2t+1) | MM(aX,bP,0,0) | read bQ(0,1)+aY(0,1,j0)
//  ph2 stage A0h0(n0)   | MM(aX,bQ,0,1) | read aY(0,1,j1..3)
//  ph3 stage B0h0(n0)   | MM(aY,bP,1,0) | read aX(1,0,j0..2)
//  ph4 stage B0h1(n0)   | MM(aY,bQ,1,1) | read aX(1,0,j3)+bP(1,0)
//  ph5 stage A0h1(n0)   | MM(aX,bP,0,0) | read bQ(1,1)+aY(1,1,j0)
//  ph6 stage A1h0(n1)   | MM(aX,bQ,0,1) | read aY(1,1,j1..3)
//  ph7 stage B1h0(n1)   | MM(aY,bP,1,0) | read aX(0,0,j0..2)'
//  ph8 stage B1h1(n1)   | MM(aY,bQ,1,1) | read aX(0,0,j3)'+bP(0,0)'
// Every read's stage-distance >= 4 (guarded by per-phase vmcnt(6)+barrier);
// every stage's slot had its last reg-read >= 2 phases earlier.
#define GEMM_MAINLOOP() do { \
    STAGE_A(0, 0, 0); STAGE_A(0, 1, 0); STAGE_B(0, 0, 0); STAGE_B(0, 1, 0); \
    STAGE_A(1, 0, 1); STAGE_B(1, 0, 1); STAGE_B(1, 1, 1); \
    asm volatile("s_waitcnt vmcnt(6)" ::: "memory"); \
    __builtin_amdgcn_s_barrier(); \
    LDAJ(aX,0,0,0); LDAJ(aX,0,0,1); LDAJ(aX,0,0,2); LDAJ(aX,0,0,3); \
    LDBH(bP,0,0); \
    _Pragma("unroll 1") \
    for (int t = 0; t < 8; ++t) { \
        const int T1 = 2 * t + 1; \
        const int n0 = (2 * t + 2 < 15) ? 2 * t + 2 : 15; \
        const int n1 = (2 * t + 3 < 15) ? 2 * t + 3 : 15; \
        STAGE_A(1, 1, T1); \
        PH_BEGIN(); MMX(aX, bP, 0, 0); PH_MMEND(); \
        LDBH(bQ, 0, 1); LDAJ(aY, 0, 1, 0); \
        PH_CLOSE(); \
        STAGE_A(0, 0, n0); \
        PH_BEGIN(); MMX(aX, bQ, 0, 1); PH_MMEND(); \
        LDAJ(aY, 0, 1, 1); LDAJ(aY, 0, 1, 2); LDAJ(aY, 0, 1, 3); \
        PH_CLOSE(); \
        STAGE_B(0, 0, n0); \
        PH_BEGIN(); MMX(aY, bP, 1, 0); PH_MMEND(); \
        LDAJ(aX, 1, 0, 0); LDAJ(aX, 1, 0, 1); LDAJ(aX, 1, 0, 2); \
        PH_CLOSE(); \
        STAGE_B(0, 1, n0); \
        PH_BEGIN(); MMX(aY, bQ, 1, 1); PH_MMEND(); \
        LDAJ(aX, 1, 0, 3); LDBH(bP, 1, 0); \
        PH_CLOSE(); \
        STAGE_A(0, 1, n0); \
        PH_BEGIN(); MMX(aX, bP, 0, 0); PH_MMEND(); \
        LDBH(bQ, 1, 1); LDAJ(aY, 1, 1, 0); \
        PH_CLOSE(); \
        STAGE_A(1, 0, n1); \
        PH_BEGIN(); MMX(aX, bQ, 0, 1); PH_MMEND(); \
        LDAJ(aY, 1, 1, 1); LDAJ(aY, 1, 1, 2); LDAJ(aY, 1, 1, 3); \
        PH_CLOSE(); \
        STAGE_B(1, 0, n1); \
        PH_BEGIN(); MMX(aY, bP, 1, 0); PH_MMEND(); \
        LDAJ(aX, 0, 0, 0); LDAJ(aX, 0, 0, 1); LDAJ(aX, 0, 0, 2); \
        PH_CLOSE(); \
        STAGE_B(1, 1, n1); \
        PH_BEGIN(); MMX(aY, bQ, 1, 1); PH_MMEND(); \
        LDAJ(aX, 0, 0, 3); LDBH(bP, 0, 0); \
        PH_CLOSE(); \
    } \
    asm volatile("s_waitcnt vmcnt(0) lgkmcnt(0)" ::: "memory"); \
} while(0)

#define GEMM_PREAMBLE() \
    const int wr = wid >> 2, wc = wid & 3; \
    const int l15 = lane & 15, l4 = lane >> 4; \
    const int Rrow = (wid << 3) + (lane >> 3); \
    const int G    = (lane & 7) ^ (lane >> 3); \
    const bf16* pA = A  + (size_t)(bm * 256 + Rrow) * 1024 + G * 8; \
    const int wc1 = Rrow >> 5, cc1 = Rrow & 31; \
    const bf16* pB = Bt + (size_t)(bn * 256 + wc1 * 64 + cc1) * 1024 + G * 8; \
    bf16* ldsA = sm + (wid << 9); \
    bf16* ldsB = sm + 32768 + (wid << 9); \
    const int g0  = l4 ^ (l15 & 7); \
    const int eA0 = wr * 4096 + l15 * 64 + g0 * 8; \
    const int eA1 = eA0 ^ 32; \
    const int eB0 = wc * 2048 + l15 * 64 + g0 * 8; \
    const int eB1 = eB0 ^ 32; \
    f32x4 acc[8][4]; \
    u32x4 aX[4][2], aY[4][2], bP[2][2], bQ[2][2]; \
    { const f32x4 zf_ = {0.f, 0.f, 0.f, 0.f}; \
      _Pragma("unroll") \
      for (int m_ = 0; m_ < 8; ++m_) \
          _Pragma("unroll") \
          for (int n_ = 0; n_ < 4; ++n_) acc[m_][n_] = zf_; }

// ======================= fused Q+KV projection GEMM =================
__global__ __launch_bounds__(512, 2) void gemm_qkv(
    const bf16* __restrict__ Aq, const bf16* __restrict__ Akv,
    const bf16* __restrict__ Wt,
    bf16* __restrict__ Qb, bf16* __restrict__ Kb, bf16* __restrict__ Vt)
{
    __shared__ bf16 sm[65536];
    const int tid = threadIdx.x, lane = tid & 63, wid = tid >> 6;

    int wg = blockIdx.x;
    {   // bijective XCD swizzle, nwg=944
        const int xcd = wg & 7, off = wg >> 3;
        wg = xcd * 118 + off;
    }
    const bool isQ = wg < 176;
    const bf16* A;  const bf16* Bt;  int bm, bn;
    if (isQ) { A = Aq;  Bt = Wt;                       bm = wg % 44;  bn = wg / 44; }
    else     { wg -= 176;
               A = Akv; Bt = Wt + (size_t)1024 * 1024; bm = wg % 96;  bn = wg / 96; }

    GEMM_PREAMBLE();
    GEMM_MAINLOOP();

    if (isQ || bn < 4) {
        bf16* C = isQ ? Qb : Kb;
        #pragma unroll
        for (int m = 0; m < 8; ++m) {
            const int row = bm * 256 + wr * 128 + m * 16 + l4 * 4;
            #pragma unroll
            for (int n = 0; n < 4; ++n) {
                const int col = bn * 256 + wc * 64 + n * 16 + l15;
                f32x4 v = acc[m][n];
                #pragma unroll
                for (int r = 0; r < 4; ++r)
                    C[(size_t)(row + r) * 1024 + col] = (bf16)v[r];
            }
        }
    } else {
        const int vb = bm / 3;
        const int j0base = (bm % 3) * 256;
        #pragma unroll
        for (int m = 0; m < 8; ++m) {
            const int j0 = j0base + wr * 128 + m * 16 + l4 * 4;
            #pragma unroll
            for (int n = 0; n < 4; ++n) {
                const int colv = (bn - 4) * 256 + wc * 64 + n * 16 + l15;
                f32x4 v = acc[m][n];
                u16x4 pk;
                #pragma unroll
                for (int r = 0; r < 4; ++r) {
                    bf16 t = (bf16)v[r];
                    pk[r] = __builtin_bit_cast(unsigned short, t);
                }
                *(u16x4*)(Vt + ((size_t)vb * 1024 + colv) * KVL + j0) = pk;
            }
        }
    }
}

// ======================= out GEMM ===================================
__global__ __launch_bounds__(512, 2) void gemm_out(
    const bf16* __restrict__ A, const bf16* __restrict__ Bt,
    float* __restrict__ Cf, const float* __restrict__ bias)
{
    __shared__ bf16 sm[65536];
    const int tid = threadIdx.x, lane = tid & 63, wid = tid >> 6;

    int wg = blockIdx.x;
    {   // nwg=176: q=22
        const int xcd = wg & 7, off = wg >> 3;
        wg = xcd * 22 + off;
    }
    const int bm = wg % 44, bn = wg / 44;

    GEMM_PREAMBLE();
    GEMM_MAINLOOP();

    #pragma unroll
    for (int m = 0; m < 8; ++m) {
        const int row = bm * 256 + wr * 128 + m * 16 + l4 * 4;
        #pragma unroll
        for (int n = 0; n < 4; ++n) {
            const int col = bn * 256 + wc * 64 + n * 16 + l15;
            f32x4 v = acc[m][n];
            const float bs = bias[col];
            #pragma unroll
            for (int r = 0; r < 4; ++r)
                Cf[(size_t)(row + r) * 1024 + col] = v[r] + bs;
        }
    }
}

// ======================= flash attention (unchanged) ================
__global__ __launch_bounds__(256, 4) void attn_fwd(
    const bf16* __restrict__ Q, const bf16* __restrict__ K,
    const bf16* __restrict__ Vt, bf16* __restrict__ O)
{
    __shared__ bf16 Kl[2][2][64][32];
    __shared__ bf16 Vl[2][2][64][32];

    const int tid = threadIdx.x, lane = tid & 63, wid = tid >> 6;
    int bid = blockIdx.x;
    const int h = bid & 15; bid >>= 4;
    const int qt = bid % 44, b = bid / 44;
    const int chunk = qt < 28 ? (qt >> 2) : 7;
    const int qrow0 = b * (TOUT * S_) +
                      (qt < 28 ? chunk * S_ + (qt & 3) * 64 : 7 * S_ + (qt - 28) * 64);

    const bf16* kg = K  + ((size_t)(b * 8 + chunk) * KVL) * 1024 + h * 64;
    const bf16* vg = Vt + ((size_t)((b * 8 + chunk) * 16 + h)) * 64 * KVL;

    const int l15 = lane & 15, l4 = lane >> 4;

    const bf16* qp = Q + (size_t)(qrow0 + wid * 16 + l15) * D_ + h * 64 + l4 * 8;
    u32x4 q0, q1;
    {
        bf16x8 t0 = *(const bf16x8*)qp;
        bf16x8 t1 = *(const bf16x8*)(qp + 32);
        #pragma unroll
        for (int j = 0; j < 8; ++j) {
            t0[j] = (bf16)((float)t0[j] * 0.125f);
            t1[j] = (bf16)((float)t1[j] * 0.125f);
        }
        q0 = __builtin_bit_cast(u32x4, t0);
        q1 = __builtin_bit_cast(u32x4, t1);
    }

    const int R   = wid * 16 + (lane >> 2);
    const int gsw = ((lane & 3) ^ ((lane >> 3) & 3)) * 8;
    const int rg  = (l4 ^ ((l15 >> 1) & 3)) * 8;

    const int baseA = ((2 * (l4 & 1)) * 16 + l15) * 4;
    const int baseB = baseA + 64;
    const bool hi2 = (l4 & 2) != 0;

    float m_s = -1e30f, l_s = 0.f;
    f32x4 oacc[4];
    const f32x4 zf = {0.f, 0.f, 0.f, 0.f};
    #pragma unroll
    for (int m2 = 0; m2 < 4; ++m2) oacc[m2] = zf;

#define ASTAGE(c, t) do { \
    const int kv0_ = (t) * 64; \
    gload_lds16(kg + (size_t)(kv0_ + R) * 1024 + gsw,      &Kl[c][0][0][0] + wid * 512); \
    gload_lds16(kg + (size_t)(kv0_ + R) * 1024 + 32 + gsw, &Kl[c][1][0][0] + wid * 512); \
    gload_lds16(vg + (size_t)R * KVL + kv0_ + gsw,         &Vl[c][0][0][0] + wid * 512); \
    gload_lds16(vg + (size_t)R * KVL + kv0_ + 32 + gsw,    &Vl[c][1][0][0] + wid * 512); \
} while (0)

    ASTAGE(0, 0);
    __syncthreads();

    #pragma unroll 1
    for (int kt = 0; kt < 12; ++kt) {
        const int cur = kt & 1;
        if (kt < 11) ASTAGE(cur ^ 1, kt + 1);

        f32x4 s[4];
        #pragma unroll
        for (int n = 0; n < 4; ++n) {
            const bf16* kp = &Kl[cur][0][n * 16 + l15][0] + rg;
            const u32x4 k0 = *(const u32x4*)kp;
            const u32x4 k1 = *(const u32x4*)(kp + 2048);
            f32x4 t = mfma16(as_bf(k0), as_bf(q0), zf);
            s[n] = mfma16(as_bf(k1), as_bf(q1), t);
        }

        float pm = s[0][0];
        #pragma unroll
        for (int n = 0; n < 4; ++n)
            #pragma unroll
            for (int r = 0; r < 4; ++r) pm = fmaxf(pm, s[n][r]);
        pm = fmaxf(pm, __shfl_xor(pm, 16));
        pm = fmaxf(pm, __shfl_xor(pm, 32));
        const float mn = fmaxf(m_s, pm);
        const float al = __expf(m_s - mn);
        m_s = mn;
        float p[4][4];
        float sum = 0.f;
        #pragma unroll
        for (int n = 0; n < 4; ++n)
            #pragma unroll
            for (int r = 0; r < 4; ++r) {
                const float e = __expf(s[n][r] - mn);
                p[n][r] = e; sum += e;
            }
        sum += __shfl_xor(sum, 16);
        sum += __shfl_xor(sum, 32);
        l_s = l_s * al + sum;
        #pragma unroll
        for (int m2 = 0; m2 < 4; ++m2) oacc[m2] *= al;

        int u[4][2];
        #pragma unroll
        for (int n = 0; n < 4; ++n) {
            u[n][0] = cvtpk(p[n][0], p[n][1]);
            u[n][1] = cvtpk(p[n][2], p[n][3]);
        }

        #pragma unroll
        for (int kk = 0; kk < 2; ++kk) {
            const int e0 = __builtin_amdgcn_ds_bpermute(baseA, u[2 * kk][0]);
            const int f0 = __builtin_amdgcn_ds_bpermute(baseA, u[2 * kk + 1][0]);
            const int e1 = __builtin_amdgcn_ds_bpermute(baseA, u[2 * kk][1]);
            const int f1 = __builtin_amdgcn_ds_bpermute(baseA, u[2 * kk + 1][1]);
            const int e2 = __builtin_amdgcn_ds_bpermute(baseB, u[2 * kk][0]);
            const int f2 = __builtin_amdgcn_ds_bpermute(baseB, u[2 * kk + 1][0]);
            const int e3 = __builtin_amdgcn_ds_bpermute(baseB, u[2 * kk][1]);
            const int f3 = __builtin_amdgcn_ds_bpermute(baseB, u[2 * kk + 1][1]);
            u32x4 pb;
            pb[0] = (unsigned)(hi2 ? f0 : e0);
            pb[1] = (unsigned)(hi2 ? f1 : e1);
            pb[2] = (unsigned)(hi2 ? f2 : e2);
            pb[3] = (unsigned)(hi2 ? f3 : e3);
            #pragma unroll
            for (int m2 = 0; m2 < 4; ++m2) {
                const u32x4 vf = *(const u32x4*)(&Vl[cur][kk][m2 * 16 + l15][0] + rg);
                oacc[m2] = mfma16(as_bf(vf), as_bf(pb), oacc[m2]);
            }
        }
        __syncthreads();
    }
#undef ASTAGE

    const float inv = 1.f / l_s;
    bf16* sc = &Kl[0][0][0][0] + wid * 1152;
    #pragma unroll
    for (int m2 = 0; m2 < 4; ++m2)
        #pragma unroll
        for (int r = 0; r < 4; ++r)
            sc[l15 * 72 + m2 * 16 + l4 * 4 + r] = (bf16)(oacc[m2][r] * inv);
    const int rq = lane >> 2, rd = (lane & 3) * 16;
    const bf16* sr = sc + rq * 72 + rd;
    const u32x4 o0 = *(const u32x4*)sr;
    const u32x4 o1 = *(const u32x4*)(sr + 8);
    bf16* op = O + (size_t)(qrow0 + wid * 16 + rq) * D_ + h * 64 + rd;
    *(u32x4*)op = o0;
    *(u32x4*)(op + 8) = o1;
}

// ======================= launch =====================================
extern "C" void kernel_launch(void* const* d_in, const int* in_sizes, int n_in,
                              void* d_out, int out_size, void* d_ws, size_t ws_size,
                              hipStream_t stream) {
    (void)in_sizes; (void)n_in; (void)out_size; (void)ws_size;
    const float* x    = (const float*)d_in[0];
    const float* Wqkv = (const float*)d_in[1];
    const float* Wout = (const float*)d_in[2];
    const float* bout = (const float*)d_in[3];

    bf16* Aq     = (bf16*)d_ws;
    bf16* Akv    = Aq     + (size_t)MQ  * 1024;
    bf16* Wqkv_t = Akv    + (size_t)MKV * 1024;
    bf16* Wout_t = Wqkv_t + (size_t)3072 * 1024;
    bf16* Qb     = Wout_t + (size_t)1024 * 1024;
    bf16* Kb     = Qb     + (size_t)MQ  * 1024;
    bf16* Vtb    = Kb     + (size_t)MKV * 1024;
    bf16* Ob     = Aq;

    prep<<<PB_TOT, 256, 0, stream>>>(x, Wqkv, Wout, Aq, Akv, Wqkv_t, Wout_t);

    gemm_qkv<<<944, 512, 0, stream>>>(Aq, Akv, Wqkv_t, Qb, Kb, Vtb);

    attn_fwd<<<4 * 44 * 16, 256, 0, stream>>>(Qb, Kb, Vtb, Ob);

    gemm_out<<<176, 512, 0, stream>>>(Ob, Wout_t, (float*)d_out, bout);
}

// Round 9
// 284.456 us; speedup vs baseline: 1.0909x; 1.0846x over previous
//
// MemFullAttention_19585050870313 — MI355X round 9
// Change vs round 8: L2-supertile block mapping in gemm_qkv/gemm_out.
//   Theory: gemm_qkv is fabric-BW-bound on A-panel re-reads (FETCH 252MB vs
//   82MB unique). Per-XCD chunks now walk 4bm x 4bn supergroups (A 2MB + B 2MB
//   = 4MB = one XCD L2), so A-panels are fetched ~once per bn-half not per bn.
//   Pure index-math change; schedule/sync structure inherited from round 5.
// prep / attn_fwd unchanged.
#include <hip/hip_runtime.h>
#include <hip/hip_bf16.h>

typedef __bf16 bf16;
typedef __bf16 bf16x8 __attribute__((ext_vector_type(8)));
typedef float  f32x4  __attribute__((ext_vector_type(4)));
typedef float  f32x4v __attribute__((ext_vector_type(4)));
typedef unsigned int u32x4 __attribute__((ext_vector_type(4)));
typedef unsigned short u16x4 __attribute__((ext_vector_type(4)));

#define DEV __device__ __forceinline__

DEV void gload_lds16(const bf16* g, bf16* l) {
    __builtin_amdgcn_global_load_lds(
        (__attribute__((address_space(1))) void*)g,
        (__attribute__((address_space(3))) void*)l, 16, 0, 0);
}

DEV bf16x8 as_bf(u32x4 v) { return __builtin_bit_cast(bf16x8, v); }

DEV f32x4 mfma16(bf16x8 a, bf16x8 b, f32x4 c) {
    return __builtin_amdgcn_mfma_f32_16x16x32_bf16(a, b, c, 0, 0, 0);
}

DEV int cvtpk(float lo, float hi) {
    int r;
    asm("v_cvt_pk_bf16_f32 %0, %1, %2" : "=v"(r) : "v"(lo), "v"(hi));
    return r;
}

// ---- problem constants (reference_length fixed at 3) ----
constexpr int D_   = 1024;
constexpr int S_   = 256;
constexpr int TOUT = 11;
constexpr int MQ   = 4 * TOUT * S_;   // 11264
constexpr int MKV  = 4 * 8 * 3 * S_;  // 24576
constexpr int KVL  = 768;

constexpr int PB_WQKV = 768;
constexpr int PB_WOUT = 256;
constexpr int PB_GQ   = MQ  * 128 / 256;     // 5632
constexpr int PB_GKV  = MKV * 128 / 256;     // 12288
constexpr int PB_TOT  = PB_WQKV + PB_WOUT + PB_GQ + PB_GKV;

// ======================= fused prep (unchanged) =====================
__global__ void prep(const float* __restrict__ x,
                     const float* __restrict__ Wqkv,
                     const float* __restrict__ Wout,
                     bf16* __restrict__ Aq, bf16* __restrict__ Akv,
                     bf16* __restrict__ Wqkv_t, bf16* __restrict__ Wout_t)
{
    __shared__ float T[64][65];
    const int tid = threadIdx.x;
    int wg = blockIdx.x;

    if (wg < PB_WQKV + PB_WOUT) {
        const float* W; bf16* Wt; int N, bid2;
        if (wg < PB_WQKV) { W = Wqkv; Wt = Wqkv_t; N = 3072; bid2 = wg; }
        else              { W = Wout; Wt = Wout_t; N = 1024; bid2 = wg - PB_WQKV; }
        const int kt = bid2 & 15, nt = bid2 >> 4;
        const int k0 = kt * 64, n0 = nt * 64;
        for (int i = 0; i < 16; ++i) {
            const int e = i * 256 + tid;
            const int kk = e >> 6, nn = e & 63;
            T[nn][kk] = W[(size_t)(k0 + kk) * N + n0 + nn];
        }
        __syncthreads();
        for (int i = 0; i < 16; ++i) {
            const int e = i * 256 + tid;
            const int n = e >> 6, kk = e & 63;
            Wt[(size_t)(n0 + n) * 1024 + k0 + kk] = (bf16)T[n][kk];
        }
        return;
    }
    wg -= PB_WQKV + PB_WOUT;

    int row, part;
    const float* src;
    bf16* dst;
    if (wg < PB_GQ) {
        const int idx = wg * 256 + tid;
        row = idx >> 7; part = idx & 127;
        const int b    = row / (TOUT * S_);
        const int r2   = row - b * (TOUT * S_);
        const int tout = r2 >> 8;
        const int s    = r2 & 255;
        const int tx   = tout < 7 ? tout * 4 : 28 + (tout - 7);
        src = x + ((size_t)((b * 32 + tx) * S_ + s)) * D_ + part * 8;
        dst = Aq + (size_t)row * D_ + part * 8;
    } else {
        const int idx = (wg - PB_GQ) * 256 + tid;
        row = idx >> 7; part = idx & 127;
        const int b  = row / 6144;
        const int r2 = row - b * 6144;
        const int c  = r2 / KVL;
        const int j  = r2 - c * KVL;
        const int f  = 1 + (j >> 8);
        const int s  = j & 255;
        const int tx = c * 4 + f;
        src = x + ((size_t)((b * 32 + tx) * S_ + s)) * D_ + part * 8;
        dst = Akv + (size_t)row * D_ + part * 8;
    }
    f32x4v v0 = *(const f32x4v*)src;
    f32x4v v1 = *(const f32x4v*)(src + 4);
    bf16x8 o;
    o[0]=(bf16)v0[0]; o[1]=(bf16)v0[1]; o[2]=(bf16)v0[2]; o[3]=(bf16)v0[3];
    o[4]=(bf16)v1[0]; o[5]=(bf16)v1[1]; o[6]=(bf16)v1[2]; o[7]=(bf16)v1[3];
    *(bf16x8*)dst = o;
}

// ======================= 8-phase GEMM, balanced read-prefetch =======
#define PH_BEGIN() do { \
    __builtin_amdgcn_s_barrier(); \
    asm volatile("s_waitcnt lgkmcnt(0)" ::: "memory"); \
    __builtin_amdgcn_sched_barrier(0); \
    __builtin_amdgcn_s_setprio(1); \
} while(0)

#define PH_MMEND() do { \
    __builtin_amdgcn_s_setprio(0); \
    __builtin_amdgcn_sched_barrier(0); \
} while(0)

#define PH_CLOSE() do { \
    asm volatile("s_waitcnt vmcnt(6)" ::: "memory"); \
    __builtin_amdgcn_s_barrier(); \
} while(0)

#define STAGE_A(bufc, half, tile) do { \
    const bf16* s0_ = pA + (size_t)(half) * 64 * 1024 + (tile) * 64; \
    bf16* d0_ = ldsA + (bufc) * 16384 + (half) * 8192; \
    gload_lds16(s0_, d0_); \
    gload_lds16(s0_ + (size_t)128 * 1024, d0_ + 4096); \
} while(0)

#define STAGE_B(bufc, half, tile) do { \
    const bf16* s0_ = pB + (size_t)(half) * 32 * 1024 + (tile) * 64; \
    bf16* d0_ = ldsB + (bufc) * 16384 + (half) * 8192; \
    gload_lds16(s0_, d0_); \
    gload_lds16(s0_ + (size_t)128 * 1024, d0_ + 4096); \
} while(0)

// 2 ds_read_b128: one A j-frag (both k-slices)
#define LDAJ(dst, bufc, mh, J) do { \
    const bf16* p_ = sm + (bufc) * 16384 + (mh) * 8192 + (J) * 1024; \
    dst[J][0] = *(const u32x4*)(p_ + eA0); \
    dst[J][1] = *(const u32x4*)(p_ + eA1); \
} while(0)

// 4 ds_read_b128: both B i-frags of one half
#define LDBH(dst, bufc, nh) do { \
    const bf16* p_ = sm + 32768 + (bufc) * 16384 + (nh) * 8192; \
    dst[0][0] = *(const u32x4*)(p_ + eB0); \
    dst[0][1] = *(const u32x4*)(p_ + eB1); \
    dst[1][0] = *(const u32x4*)(p_ + 1024 + eB0); \
    dst[1][1] = *(const u32x4*)(p_ + 1024 + eB1); \
} while(0)

#define MMX(av, bv, mh, nh) do { \
    _Pragma("unroll") \
    for (int j_ = 0; j_ < 4; ++j_) { \
        _Pragma("unroll") \
        for (int i_ = 0; i_ < 2; ++i_) { \
            f32x4 c_ = acc[(mh)*4 + j_][(nh)*2 + i_]; \
            c_ = mfma16(as_bf(av[j_][0]), as_bf(bv[i_][0]), c_); \
            c_ = mfma16(as_bf(av[j_][1]), as_bf(bv[i_][1]), c_); \
            acc[(mh)*4 + j_][(nh)*2 + i_] = c_; \
        } \
    } \
} while(0)

#define GEMM_MAINLOOP() do { \
    STAGE_A(0, 0, 0); STAGE_A(0, 1, 0); STAGE_B(0, 0, 0); STAGE_B(0, 1, 0); \
    STAGE_A(1, 0, 1); STAGE_B(1, 0, 1); STAGE_B(1, 1, 1); \
    asm volatile("s_waitcnt vmcnt(6)" ::: "memory"); \
    __builtin_amdgcn_s_barrier(); \
    LDAJ(aX,0,0,0); LDAJ(aX,0,0,1); LDAJ(aX,0,0,2); LDAJ(aX,0,0,3); \
    LDBH(bP,0,0); \
    _Pragma("unroll 1") \
    for (int t = 0; t < 8; ++t) { \
        const int T1 = 2 * t + 1; \
        const int n0 = (2 * t + 2 < 15) ? 2 * t + 2 : 15; \
        const int n1 = (2 * t + 3 < 15) ? 2 * t + 3 : 15; \
        STAGE_A(1, 1, T1); \
        PH_BEGIN(); MMX(aX, bP, 0, 0); PH_MMEND(); \
        LDBH(bQ, 0, 1); LDAJ(aY, 0, 1, 0); \
        PH_CLOSE(); \
        STAGE_A(0, 0, n0); \
        PH_BEGIN(); MMX(aX, bQ, 0, 1); PH_MMEND(); \
        LDAJ(aY, 0, 1, 1); LDAJ(aY, 0, 1, 2); LDAJ(aY, 0, 1, 3); \
        PH_CLOSE(); \
        STAGE_B(0, 0, n0); \
        PH_BEGIN(); MMX(aY, bP, 1, 0); PH_MMEND(); \
        LDAJ(aX, 1, 0, 0); LDAJ(aX, 1, 0, 1); LDAJ(aX, 1, 0, 2); \
        PH_CLOSE(); \
        STAGE_B(0, 1, n0); \
        PH_BEGIN(); MMX(aY, bQ, 1, 1); PH_MMEND(); \
        LDAJ(aX, 1, 0, 3); LDBH(bP, 1, 0); \
        PH_CLOSE(); \
        STAGE_A(0, 1, n0); \
        PH_BEGIN(); MMX(aX, bP, 0, 0); PH_MMEND(); \
        LDBH(bQ, 1, 1); LDAJ(aY, 1, 1, 0); \
        PH_CLOSE(); \
        STAGE_A(1, 0, n1); \
        PH_BEGIN(); MMX(aX, bQ, 0, 1); PH_MMEND(); \
        LDAJ(aY, 1, 1, 1); LDAJ(aY, 1, 1, 2); LDAJ(aY, 1, 1, 3); \
        PH_CLOSE(); \
        STAGE_B(1, 0, n1); \
        PH_BEGIN(); MMX(aY, bP, 1, 0); PH_MMEND(); \
        LDAJ(aX, 0, 0, 0); LDAJ(aX, 0, 0, 1); LDAJ(aX, 0, 0, 2); \
        PH_CLOSE(); \
        STAGE_B(1, 1, n1); \
        PH_BEGIN(); MMX(aY, bQ, 1, 1); PH_MMEND(); \
        LDAJ(aX, 0, 0, 3); LDBH(bP, 0, 0); \
        PH_CLOSE(); \
    } \
    asm volatile("s_waitcnt vmcnt(0) lgkmcnt(0)" ::: "memory"); \
} while(0)

#define GEMM_PREAMBLE() \
    const int wr = wid >> 2, wc = wid & 3; \
    const int l15 = lane & 15, l4 = lane >> 4; \
    const int Rrow = (wid << 3) + (lane >> 3); \
    const int G    = (lane & 7) ^ (lane >> 3); \
    const bf16* pA = A  + (size_t)(bm * 256 + Rrow) * 1024 + G * 8; \
    const int wc1 = Rrow >> 5, cc1 = Rrow & 31; \
    const bf16* pB = Bt + (size_t)(bn * 256 + wc1 * 64 + cc1) * 1024 + G * 8; \
    bf16* ldsA = sm + (wid << 9); \
    bf16* ldsB = sm + 32768 + (wid << 9); \
    const int g0  = l4 ^ (l15 & 7); \
    const int eA0 = wr * 4096 + l15 * 64 + g0 * 8; \
    const int eA1 = eA0 ^ 32; \
    const int eB0 = wc * 2048 + l15 * 64 + g0 * 8; \
    const int eB1 = eB0 ^ 32; \
    f32x4 acc[8][4]; \
    u32x4 aX[4][2], aY[4][2], bP[2][2], bQ[2][2]; \
    { const f32x4 zf_ = {0.f, 0.f, 0.f, 0.f}; \
      _Pragma("unroll") \
      for (int m_ = 0; m_ < 8; ++m_) \
          _Pragma("unroll") \
          for (int n_ = 0; n_ < 4; ++n_) acc[m_][n_] = zf_; }

// ======================= fused Q+KV projection GEMM =================
__global__ __launch_bounds__(512, 2) void gemm_qkv(
    const bf16* __restrict__ Aq, const bf16* __restrict__ Akv,
    const bf16* __restrict__ Wt,
    bf16* __restrict__ Qb, bf16* __restrict__ Kb, bf16* __restrict__ Vt)
{
    __shared__ bf16 sm[65536];
    const int tid = threadIdx.x, lane = tid & 63, wid = tid >> 6;

    int wg = blockIdx.x;
    {   // bijective XCD swizzle, nwg=944
        const int xcd = wg & 7, off = wg >> 3;
        wg = xcd * 118 + off;
    }
    const bool isQ = wg < 176;
    const bf16* A;  const bf16* Bt;  int bm, bn;
    if (isQ) {
        // L2-supertile: 4bm x 4bn groups (A 2MB + B 2MB = 4MB = XCD L2)
        const int sg = wg >> 4, s = wg & 15;      // 11 groups x 16
        bm = sg * 4 + (s >> 2);                   // [0,44)
        bn = s & 3;                               // [0,4)
        A = Aq;  Bt = Wt;
    } else {
        const int id2 = wg - 176;
        const int sg = id2 >> 4, s = id2 & 15;    // 48 groups x 16
        bm = (sg % 24) * 4 + (s >> 2);            // [0,96)
        bn = (sg / 24) * 4 + (s & 3);             // [0,8): bn-half sweeps
        A = Akv; Bt = Wt + (size_t)1024 * 1024;
    }

    GEMM_PREAMBLE();
    GEMM_MAINLOOP();

    if (isQ || bn < 4) {
        bf16* C = isQ ? Qb : Kb;
        #pragma unroll
        for (int m = 0; m < 8; ++m) {
            const int row = bm * 256 + wr * 128 + m * 16 + l4 * 4;
            #pragma unroll
            for (int n = 0; n < 4; ++n) {
                const int col = bn * 256 + wc * 64 + n * 16 + l15;
                f32x4 v = acc[m][n];
                #pragma unroll
                for (int r = 0; r < 4; ++r)
                    C[(size_t)(row + r) * 1024 + col] = (bf16)v[r];
            }
        }
    } else {
        const int vb = bm / 3;
        const int j0base = (bm % 3) * 256;
        #pragma unroll
        for (int m = 0; m < 8; ++m) {
            const int j0 = j0base + wr * 128 + m * 16 + l4 * 4;
            #pragma unroll
            for (int n = 0; n < 4; ++n) {
                const int colv = (bn - 4) * 256 + wc * 64 + n * 16 + l15;
                f32x4 v = acc[m][n];
                u16x4 pk;
                #pragma unroll
                for (int r = 0; r < 4; ++r) {
                    bf16 t = (bf16)v[r];
                    pk[r] = __builtin_bit_cast(unsigned short, t);
                }
                *(u16x4*)(Vt + ((size_t)vb * 1024 + colv) * KVL + j0) = pk;
            }
        }
    }
}

// ======================= out GEMM ===================================
__global__ __launch_bounds__(512, 2) void gemm_out(
    const bf16* __restrict__ A, const bf16* __restrict__ Bt,
    float* __restrict__ Cf, const float* __restrict__ bias)
{
    __shared__ bf16 sm[65536];
    const int tid = threadIdx.x, lane = tid & 63, wid = tid >> 6;

    int wg = blockIdx.x;
    {   // nwg=176: q=22
        const int xcd = wg & 7, off = wg >> 3;
        wg = xcd * 22 + off;
    }
    // L2-supertile: 4bm x 4bn groups
    const int sg = wg >> 4, s = wg & 15;
    const int bm = sg * 4 + (s >> 2), bn = s & 3;

    GEMM_PREAMBLE();
    GEMM_MAINLOOP();

    #pragma unroll
    for (int m = 0; m < 8; ++m) {
        const int row = bm * 256 + wr * 128 + m * 16 + l4 * 4;
        #pragma unroll
        for (int n = 0; n < 4; ++n) {
            const int col = bn * 256 + wc * 64 + n * 16 + l15;
            f32x4 v = acc[m][n];
            const float bs = bias[col];
            #pragma unroll
            for (int r = 0; r < 4; ++r)
                Cf[(size_t)(row + r) * 1024 + col] = v[r] + bs;
        }
    }
}

// ======================= flash attention (unchanged) ================
__global__ __launch_bounds__(256, 4) void attn_fwd(
    const bf16* __restrict__ Q, const bf16* __restrict__ K,
    const bf16* __restrict__ Vt, bf16* __restrict__ O)
{
    __shared__ bf16 Kl[2][2][64][32];
    __shared__ bf16 Vl[2][2][64][32];

    const int tid = threadIdx.x, lane = tid & 63, wid = tid >> 6;
    int bid = blockIdx.x;
    const int h = bid & 15; bid >>= 4;
    const int qt = bid % 44, b = bid / 44;
    const int chunk = qt < 28 ? (qt >> 2) : 7;
    const int qrow0 = b * (TOUT * S_) +
                      (qt < 28 ? chunk * S_ + (qt & 3) * 64 : 7 * S_ + (qt - 28) * 64);

    const bf16* kg = K  + ((size_t)(b * 8 + chunk) * KVL) * 1024 + h * 64;
    const bf16* vg = Vt + ((size_t)((b * 8 + chunk) * 16 + h)) * 64 * KVL;

    const int l15 = lane & 15, l4 = lane >> 4;

    const bf16* qp = Q + (size_t)(qrow0 + wid * 16 + l15) * D_ + h * 64 + l4 * 8;
    u32x4 q0, q1;
    {
        bf16x8 t0 = *(const bf16x8*)qp;
        bf16x8 t1 = *(const bf16x8*)(qp + 32);
        #pragma unroll
        for (int j = 0; j < 8; ++j) {
            t0[j] = (bf16)((float)t0[j] * 0.125f);
            t1[j] = (bf16)((float)t1[j] * 0.125f);
        }
        q0 = __builtin_bit_cast(u32x4, t0);
        q1 = __builtin_bit_cast(u32x4, t1);
    }

    const int R   = wid * 16 + (lane >> 2);
    const int gsw = ((lane & 3) ^ ((lane >> 3) & 3)) * 8;
    const int rg  = (l4 ^ ((l15 >> 1) & 3)) * 8;

    const int baseA = ((2 * (l4 & 1)) * 16 + l15) * 4;
    const int baseB = baseA + 64;
    const bool hi2 = (l4 & 2) != 0;

    float m_s = -1e30f, l_s = 0.f;
    f32x4 oacc[4];
    const f32x4 zf = {0.f, 0.f, 0.f, 0.f};
    #pragma unroll
    for (int m2 = 0; m2 < 4; ++m2) oacc[m2] = zf;

#define ASTAGE(c, t) do { \
    const int kv0_ = (t) * 64; \
    gload_lds16(kg + (size_t)(kv0_ + R) * 1024 + gsw,      &Kl[c][0][0][0] + wid * 512); \
    gload_lds16(kg + (size_t)(kv0_ + R) * 1024 + 32 + gsw, &Kl[c][1][0][0] + wid * 512); \
    gload_lds16(vg + (size_t)R * KVL + kv0_ + gsw,         &Vl[c][0][0][0] + wid * 512); \
    gload_lds16(vg + (size_t)R * KVL + kv0_ + 32 + gsw,    &Vl[c][1][0][0] + wid * 512); \
} while (0)

    ASTAGE(0, 0);
    __syncthreads();

    #pragma unroll 1
    for (int kt = 0; kt < 12; ++kt) {
        const int cur = kt & 1;
        if (kt < 11) ASTAGE(cur ^ 1, kt + 1);

        f32x4 s[4];
        #pragma unroll
        for (int n = 0; n < 4; ++n) {
            const bf16* kp = &Kl[cur][0][n * 16 + l15][0] + rg;
            const u32x4 k0 = *(const u32x4*)kp;
            const u32x4 k1 = *(const u32x4*)(kp + 2048);
            f32x4 t = mfma16(as_bf(k0), as_bf(q0), zf);
            s[n] = mfma16(as_bf(k1), as_bf(q1), t);
        }

        float pm = s[0][0];
        #pragma unroll
        for (int n = 0; n < 4; ++n)
            #pragma unroll
            for (int r = 0; r < 4; ++r) pm = fmaxf(pm, s[n][r]);
        pm = fmaxf(pm, __shfl_xor(pm, 16));
        pm = fmaxf(pm, __shfl_xor(pm, 32));
        const float mn = fmaxf(m_s, pm);
        const float al = __expf(m_s - mn);
        m_s = mn;
        float p[4][4];
        float sum = 0.f;
        #pragma unroll
        for (int n = 0; n < 4; ++n)
            #pragma unroll
            for (int r = 0; r < 4; ++r) {
                const float e = __expf(s[n][r] - mn);
                p[n][r] = e; sum += e;
            }
        sum += __shfl_xor(sum, 16);
        sum += __shfl_xor(sum, 32);
        l_s = l_s * al + sum;
        #pragma unroll
        for (int m2 = 0; m2 < 4; ++m2) oacc[m2] *= al;

        int u[4][2];
        #pragma unroll
        for (int n = 0; n < 4; ++n) {
            u[n][0] = cvtpk(p[n][0], p[n][1]);
            u[n][1] = cvtpk(p[n][2], p[n][3]);
        }

        #pragma unroll
        for (int kk = 0; kk < 2; ++kk) {
            const int e0 = __builtin_amdgcn_ds_bpermute(baseA, u[2 * kk][0]);
            const int f0 = __builtin_amdgcn_ds_bpermute(baseA, u[2 * kk + 1][0]);
            const int e1 = __builtin_amdgcn_ds_bpermute(baseA, u[2 * kk][1]);
            const int f1 = __builtin_amdgcn_ds_bpermute(baseA, u[2 * kk + 1][1]);
            const int e2 = __builtin_amdgcn_ds_bpermute(baseB, u[2 * kk][0]);
            const int f2 = __builtin_amdgcn_ds_bpermute(baseB, u[2 * kk + 1][0]);
            const int e3 = __builtin_amdgcn_ds_bpermute(baseB, u[2 * kk][1]);
            const int f3 = __builtin_amdgcn_ds_bpermute(baseB, u[2 * kk + 1][1]);
            u32x4 pb;
            pb[0] = (unsigned)(hi2 ? f0 : e0);
            pb[1] = (unsigned)(hi2 ? f1 : e1);
            pb[2] = (unsigned)(hi2 ? f2 : e2);
            pb[3] = (unsigned)(hi2 ? f3 : e3);
            #pragma unroll
            for (int m2 = 0; m2 < 4; ++m2) {
                const u32x4 vf = *(const u32x4*)(&Vl[cur][kk][m2 * 16 + l15][0] + rg);
                oacc[m2] = mfma16(as_bf(vf), as_bf(pb), oacc[m2]);
            }
        }
        __syncthreads();
    }
#undef ASTAGE

    const float inv = 1.f / l_s;
    bf16* sc = &Kl[0][0][0][0] + wid * 1152;
    #pragma unroll
    for (int m2 = 0; m2 < 4; ++m2)
        #pragma unroll
        for (int r = 0; r < 4; ++r)
            sc[l15 * 72 + m2 * 16 + l4 * 4 + r] = (bf16)(oacc[m2][r] * inv);
    const int rq = lane >> 2, rd = (lane & 3) * 16;
    const bf16* sr = sc + rq * 72 + rd;
    const u32x4 o0 = *(const u32x4*)sr;
    const u32x4 o1 = *(const u32x4*)(sr + 8);
    bf16* op = O + (size_t)(qrow0 + wid * 16 + rq) * D_ + h * 64 + rd;
    *(u32x4*)op = o0;
    *(u32x4*)(op + 8) = o1;
}

// ======================= launch =====================================
extern "C" void kernel_launch(void* const* d_in, const int* in_sizes, int n_in,
                              void* d_out, int out_size, void* d_ws, size_t ws_size,
                              hipStream_t stream) {
    (void)in_sizes; (void)n_in; (void)out_size; (void)ws_size;
    const float* x    = (const float*)d_in[0];
    const float* Wqkv = (const float*)d_in[1];
    const float* Wout = (const float*)d_in[2];
    const float* bout = (const float*)d_in[3];

    bf16* Aq     = (bf16*)d_ws;
    bf16* Akv    = Aq     + (size_t)MQ  * 1024;
    bf16* Wqkv_t = Akv    + (size_t)MKV * 1024;
    bf16* Wout_t = Wqkv_t + (size_t)3072 * 1024;
    bf16* Qb     = Wout_t + (size_t)1024 * 1024;
    bf16* Kb     = Qb     + (size_t)MQ  * 1024;
    bf16* Vtb    = Kb     + (size_t)MKV * 1024;
    bf16* Ob     = Aq;

    prep<<<PB_TOT, 256, 0, stream>>>(x, Wqkv, Wout, Aq, Akv, Wqkv_t, Wout_t);

    gemm_qkv<<<944, 512, 0, stream>>>(Aq, Akv, Wqkv_t, Qb, Kb, Vtb);

    attn_fwd<<<4 * 44 * 16, 256, 0, stream>>>(Qb, Kb, Vtb, Ob);

    gemm_out<<<176, 512, 0, stream>>>(Ob, Wout_t, (float*)d_out, bout);
}